// Round 1
// baseline (28387.402 us; speedup 1.0000x reference)
//
#include <hip/hip_runtime.h>
#include <math.h>

__device__ __forceinline__ float sigmf(float x){ return 1.f/(1.f+expf(-x)); }

// ---------------- fused conv + bias + relu + maxpool ----------------
// one thread per pooled output (b,co,hp,wp); weights for co staged in LDS
template<int KW, int PKH, int PKW>
__launch_bounds__(64)
__global__ void conv_pool(const float* __restrict__ in, const float* __restrict__ wgt,
                          const float* __restrict__ bias, float* __restrict__ out,
                          int Cin, int H, int W, int Cout,
                          int pad, int Hp, int Wp, int psh, int psw)
{
    extern __shared__ float sw[];
    const int tid = threadIdx.x;
    const int bco = blockIdx.z;               // b*Cout + co
    const int co  = bco % Cout;
    const int nw  = Cin*KW*KW;
    {
        const float* wsrc = wgt + (size_t)co*nw;
        for (int i = tid; i < nw; i += 64) sw[i] = wsrc[i];
    }
    __syncthreads();
    const int wp = blockIdx.x*64 + tid;
    if (wp >= Wp) return;
    const int hp = blockIdx.y;
    const int b  = bco / Cout;
    constexpr int PH = PKH + KW - 1;
    constexpr int PW = PKW + KW - 1;
    const int y0 = hp*psh - pad;
    const int x0 = wp*psw - pad;
    int yo[PH]; bool ym[PH];
#pragma unroll
    for (int py=0; py<PH; ++py){ int y=y0+py; ym[py]=(y>=0)&&(y<H); yo[py]=y*W; }
    int xo[PW]; bool xm[PW];
#pragma unroll
    for (int px=0; px<PW; ++px){ int x=x0+px; xm[px]=(x>=0)&&(x<W); xo[px]=x; }
    float acc[PKH][PKW];
#pragma unroll
    for (int i=0;i<PKH;++i)
#pragma unroll
        for (int j=0;j<PKW;++j) acc[i][j]=0.f;

    const float* ip = in + (size_t)b*Cin*H*W;
    for (int ci=0; ci<Cin; ++ci, ip += (size_t)H*W) {
        float patch[PH][PW];
#pragma unroll
        for (int py=0; py<PH; ++py)
#pragma unroll
            for (int px=0; px<PW; ++px)
                patch[py][px] = (ym[py]&&xm[px]) ? ip[yo[py]+xo[px]] : 0.f;
        const float* wr = sw + ci*KW*KW;
#pragma unroll
        for (int ky=0; ky<KW; ++ky)
#pragma unroll
            for (int kx=0; kx<KW; ++kx) {
                float wv = wr[ky*KW+kx];
#pragma unroll
                for (int ph=0; ph<PKH; ++ph)
#pragma unroll
                    for (int pw2=0; pw2<PKW; ++pw2)
                        acc[ph][pw2] = fmaf(patch[ph+ky][pw2+kx], wv, acc[ph][pw2]);
            }
    }
    const float bv = bias[co];
    float m = -1e30f;
#pragma unroll
    for (int ph=0; ph<PKH; ++ph)
#pragma unroll
        for (int pw2=0; pw2<PKW; ++pw2) m = fmaxf(m, acc[ph][pw2]+bv);
    m = fmaxf(m, 0.f);   // relu(max) == max(relu)
    out[((size_t)bco*Hp + hp)*Wp + wp] = m;
}

// ---------------- generic fp32 GEMM: C[M,N] = A[M,K] * B[N,K]^T (+bias1+bias2) ----------------
__launch_bounds__(256)
__global__ void gemm_nt(const float* __restrict__ A, const float* __restrict__ Bm,
                        const float* __restrict__ bias1, const float* __restrict__ bias2,
                        float* __restrict__ C, int M, int N, int K)
{
    __shared__ float As[16][65];
    __shared__ float Bs[16][65];
    const int tid = threadIdx.x;
    const int tx = tid & 15, ty = tid >> 4;
    const int row0 = blockIdx.y*64, col0 = blockIdx.x*64;
    float acc[4][4] = {};
    for (int k0 = 0; k0 < K; k0 += 16) {
#pragma unroll
        for (int i = 0; i < 4; ++i) {
            int e  = tid + i*256;          // 1024 elements = 64 rows x 16 k
            int r  = e >> 4, kk = e & 15;
            int gr = row0 + r, gk = k0 + kk;
            As[kk][r] = (gr < M) ? A[(size_t)gr*K + gk] : 0.f;
            int gc = col0 + r;
            Bs[kk][r] = (gc < N) ? Bm[(size_t)gc*K + gk] : 0.f;
        }
        __syncthreads();
#pragma unroll
        for (int kk = 0; kk < 16; ++kk) {
            float av[4], bv[4];
#pragma unroll
            for (int i=0;i<4;++i) av[i] = As[kk][ty*4+i];
#pragma unroll
            for (int j=0;j<4;++j) bv[j] = Bs[kk][tx*4+j];
#pragma unroll
            for (int i=0;i<4;++i)
#pragma unroll
                for (int j=0;j<4;++j) acc[i][j] = fmaf(av[i], bv[j], acc[i][j]);
        }
        __syncthreads();
    }
#pragma unroll
    for (int i=0;i<4;++i)
#pragma unroll
        for (int j=0;j<4;++j) {
            int r = row0 + ty*4 + i, cc = col0 + tx*4 + j;
            if (r < M && cc < N) {
                float v = acc[i][j];
                if (bias1) v += bias1[cc];
                if (bias2) v += bias2[cc];
                C[(size_t)r*N + cc] = v;
            }
        }
}

// ---------------- transposes ----------------
__global__ void transpose2d(const float* __restrict__ in, float* __restrict__ out, int R, int C)
{
    int idx = blockIdx.x*256 + threadIdx.x;
    if (idx >= R*C) return;
    int r = idx / C, c = idx % C;
    out[(size_t)c*R + r] = in[idx];
}

__global__ void transpose_whh(const float* __restrict__ in, float* __restrict__ out)
{
    // in [8][1024][256] -> out [8][256][1024]
    int idx = blockIdx.x*256 + threadIdx.x;
    if (idx >= 8*1024*256) return;
    int l = idx / 262144, rem = idx % 262144;
    int g = rem >> 8, k = rem & 255;
    out[(size_t)l*262144 + k*1024 + g] = in[idx];
}

__global__ void transpose_c7(const float* __restrict__ in, float* __restrict__ out)
{
    // in [16][512][61] -> out [16][61][512]
    int idx = blockIdx.x*256 + threadIdx.x;
    if (idx >= 16*512*61) return;
    int b = idx / (512*61), rem = idx % (512*61);
    int c = rem / 61, t = rem % 61;
    out[((size_t)b*61 + t)*512 + c] = in[idx];
}

// ---------------- LSTM scan: one block per (batch, direction), 256 threads = hidden units ----------------
__launch_bounds__(256)
__global__ void lstm_scan(const float* __restrict__ xgf, const float* __restrict__ xgb,
                          const float* __restrict__ wTf, const float* __restrict__ wTb,
                          float* __restrict__ hout, int T)
{
    __shared__ float hs[256];
    const int b = blockIdx.x, dir = blockIdx.y, j = threadIdx.x;
    const float* xg = dir ? xgb : xgf;
    const float* wT = dir ? wTb : wTf;      // [256 k][1024 g]
    float c = 0.f;
    hs[j] = 0.f;
    __syncthreads();
    float* outp = hout + dir*256 + j;
    for (int s = 0; s < T; ++s) {
        int t = dir ? (T-1-s) : s;
        const float* xr = xg + ((size_t)b*T + t)*1024;
        float gi = xr[j], gf = xr[256+j], gg = xr[512+j], go = xr[768+j];
#pragma unroll 4
        for (int k = 0; k < 256; ++k) {
            float h = hs[k];
            const float* w = wT + k*1024 + j;
            gi = fmaf(h, w[0],   gi);
            gf = fmaf(h, w[256], gf);
            gg = fmaf(h, w[512], gg);
            go = fmaf(h, w[768], go);
        }
        float i_ = sigmf(gi), f_ = sigmf(gf), g_ = tanhf(gg), o_ = sigmf(go);
        c = f_*c + i_*g_;
        float h = o_*tanhf(c);
        __syncthreads();       // everyone done reading hs
        hs[j] = h;
        __syncthreads();
        outp[((size_t)b*T + t)*512] = h;
    }
}

// ---------------- fused attention decoder: one block per batch, 25 steps internal ----------------
__launch_bounds__(512)
__global__ void decoder_kernel(const float* __restrict__ seq,   // [16][61][512]
                               const float* __restrict__ enc,   // [16][61][256]
                               const float* __restrict__ dpwT,  // [512][256]
                               const float* __restrict__ dec_proj_b,
                               const float* __restrict__ vw,    // [256]
                               const float* __restrict__ wihT,  // [512][2048]
                               const float* __restrict__ whhT,  // [512][2048]
                               const float* __restrict__ bih, const float* __restrict__ bhh,
                               const float* __restrict__ dwT,   // [512][99]
                               const float* __restrict__ dense_b,
                               float* __restrict__ out, int T)
{
    const int b = blockIdx.x, tid = threadIdx.x;   // 512 threads
    __shared__ float h[512], c[512], dec[256], sc[64], ctx[512];
    h[tid] = 0.f; c[tid] = 0.f;
    __syncthreads();
    for (int step = 0; step < 25; ++step) {
        // dec = h @ dec_proj_w^T + b
        if (tid < 256) {
            float s = dec_proj_b[tid];
            for (int k = 0; k < 512; ++k) s = fmaf(h[k], dpwT[k*256 + tid], s);
            dec[tid] = s;
        }
        __syncthreads();
        // scores[t] = v . tanh(enc[t]+dec): 8 threads per t
        {
            int t = tid >> 3, sub = tid & 7;
            float p = 0.f;
            if (t < T) {
                const float* er = enc + ((size_t)b*T + t)*256;
                for (int a = sub*32; a < sub*32 + 32; ++a)
                    p = fmaf(tanhf(er[a] + dec[a]), vw[a], p);
            }
            p += __shfl_xor(p, 1, 8); p += __shfl_xor(p, 2, 8); p += __shfl_xor(p, 4, 8);
            if (t < T && sub == 0) sc[t] = p;
        }
        __syncthreads();
        // softmax over T by wave 0
        if (tid < 64) {
            float v = (tid < T) ? sc[tid] : -1e30f;
            float m = v;
            for (int o = 1; o < 64; o <<= 1) m = fmaxf(m, __shfl_xor(m, o, 64));
            float e = (tid < T) ? expf(v - m) : 0.f;
            float s = e;
            for (int o = 1; o < 64; o <<= 1) s += __shfl_xor(s, o, 64);
            if (tid < T) sc[tid] = e / s;
        }
        __syncthreads();
        // ctx = aw @ seq
        {
            float s = 0.f;
            const float* sr = seq + (size_t)b*T*512 + tid;
            for (int t = 0; t < T; ++t) s = fmaf(sc[t], sr[(size_t)t*512], s);
            ctx[tid] = s;
        }
        __syncthreads();
        // gates (thread j owns hidden unit j)
        float gi = bih[tid]       + bhh[tid];
        float gf = bih[512+tid]   + bhh[512+tid];
        float gg = bih[1024+tid]  + bhh[1024+tid];
        float go = bih[1536+tid]  + bhh[1536+tid];
#pragma unroll 2
        for (int k = 0; k < 512; ++k) {
            float cv = ctx[k], hv = h[k];
            const float* wi = wihT + (size_t)k*2048;
            const float* wh = whhT + (size_t)k*2048;
            gi = fmaf(cv, wi[tid],      fmaf(hv, wh[tid],      gi));
            gf = fmaf(cv, wi[512+tid],  fmaf(hv, wh[512+tid],  gf));
            gg = fmaf(cv, wi[1024+tid], fmaf(hv, wh[1024+tid], gg));
            go = fmaf(cv, wi[1536+tid], fmaf(hv, wh[1536+tid], go));
        }
        float i_ = sigmf(gi), f_ = sigmf(gf), g_ = tanhf(gg), o_ = sigmf(go);
        float cn = f_*c[tid] + i_*g_;
        float hn = o_*tanhf(cn);
        __syncthreads();   // everyone done reading h
        c[tid] = cn; h[tid] = hn;
        __syncthreads();
        // dense: 4 threads per output j
        {
            int j = tid >> 2, sub = tid & 3;
            float p = 0.f;
            if (j < 99) {
                for (int k = sub*128; k < sub*128 + 128; ++k)
                    p = fmaf(h[k], dwT[k*99 + j], p);
            }
            p += __shfl_xor(p, 1, 4); p += __shfl_xor(p, 2, 4);
            if (j < 99 && sub == 0) out[((size_t)step*16 + b)*99 + j] = p + dense_b[j];
        }
        __syncthreads();
    }
}

// ---------------- launch ----------------
extern "C" void kernel_launch(void* const* d_in, const int* in_sizes, int n_in,
                              void* d_out, int out_size, void* d_ws, size_t ws_size,
                              hipStream_t stream)
{
    (void)in_sizes; (void)n_in; (void)out_size; (void)ws_size;
    const float* x = (const float*)d_in[0];
    const float* convw[7]; const float* convb[7];
    for (int i = 0; i < 7; ++i) { convw[i] = (const float*)d_in[1+2*i]; convb[i] = (const float*)d_in[2+2*i]; }
    const float* lw   = (const float*)d_in[15];
    const float* lr   = (const float*)d_in[16];
    const float* lbi  = (const float*)d_in[17];
    const float* lbh  = (const float*)d_in[18];
    const float* encW = (const float*)d_in[19];
    const float* encB = (const float*)d_in[20];
    const float* dpw  = (const float*)d_in[21];
    const float* dpb  = (const float*)d_in[22];
    const float* vw   = (const float*)d_in[23];
    const float* dwih = (const float*)d_in[24];
    const float* dwhh = (const float*)d_in[25];
    const float* dbih = (const float*)d_in[26];
    const float* dbhh = (const float*)d_in[27];
    const float* dnw  = (const float*)d_in[28];
    const float* dnb  = (const float*)d_in[29];
    float* outp = (float*)d_out;

    float* ws    = (float*)d_ws;
    float* bufA  = ws;                      // 16,777,216 floats
    float* bufB  = ws + 16777216;           //  8,388,608 floats, carved below after convs
    float* seq_x = bufB;                    // 499,712
    float* seq_y = bufB + 499712;           // 499,712
    float* xg_f  = bufB + 999424;           // 999,424
    float* xg_b  = bufB + 1998848;          // 999,424
    float* whhT  = bufB + 2998272;          // 2,097,152 (8 x 256 x 1024)
    float* encb  = bufB + 5095424;          // 249,856
    float* dpwT  = bufB + 5345280;          // 131,072
    float* wihT  = bufB + 5476352;          // 1,048,576
    float* whh2T = bufB + 6524928;          // 1,048,576
    float* dwT   = bufB + 7573504;          // 50,688  (end 7,624,192 < 8,388,608)

    // ---- convs ----
    const int cins[7]  = {1,64,128,256,512,512,512};
    const int couts[7] = {64,128,256,512,512,512,512};
    const int Ks[7]    = {3,3,3,3,3,3,2};
    const int pads[7]  = {1,1,1,1,1,1,0};
    const int pkh[7]   = {2,2,2,2,2,2,1};
    const int pshv[7]  = {2,2,2,2,2,2,1};
    const int pswv[7]  = {2,2,1,1,2,1,1};
    int H = 128, W = 512;
    const float* src = x;
    float* dsts[7] = {bufA, bufB, bufA, bufB, bufA, bufB, bufA};
    for (int i = 0; i < 7; ++i) {
        int Hc = H + 2*pads[i] - Ks[i] + 1;
        int Wc = W + 2*pads[i] - Ks[i] + 1;
        int Hp = (Hc - pkh[i]) / pshv[i] + 1;
        int Wp = (Wc - pkh[i]) / pswv[i] + 1;
        dim3 grid((Wp + 63)/64, Hp, 16*couts[i]);
        size_t shmem = (size_t)cins[i]*Ks[i]*Ks[i]*sizeof(float);
        if (i < 6)
            conv_pool<3,2,2><<<grid, 64, shmem, stream>>>(src, convw[i], convb[i], dsts[i],
                cins[i], H, W, couts[i], pads[i], Hp, Wp, pshv[i], pswv[i]);
        else
            conv_pool<2,1,1><<<grid, 64, shmem, stream>>>(src, convw[i], convb[i], dsts[i],
                cins[i], H, W, couts[i], pads[i], Hp, Wp, pshv[i], pswv[i]);
        src = dsts[i]; H = Hp; W = Wp;
    }
    // src = bufA = [16][512][1][61]

    // ---- reshape to [B,T,512] ----
    transpose_c7<<<(16*512*61 + 255)/256, 256, 0, stream>>>(bufA, seq_x);

    // ---- weight transposes ----
    transpose_whh<<<(8*1024*256 + 255)/256, 256, 0, stream>>>(lr, whhT);
    transpose2d<<<(256*512 + 255)/256, 256, 0, stream>>>(dpw,  dpwT, 256, 512);
    transpose2d<<<(2048*512 + 255)/256, 256, 0, stream>>>(dwih, wihT, 2048, 512);
    transpose2d<<<(2048*512 + 255)/256, 256, 0, stream>>>(dwhh, whh2T, 2048, 512);
    transpose2d<<<(99*512 + 255)/256, 256, 0, stream>>>(dnw,  dwT, 99, 512);

    // ---- 4 BiLSTM layers ----
    const int T = 61, M = 16*T;
    float* cur = seq_x; float* nxt = seq_y;
    for (int L = 0; L < 4; ++L) {
        int s0 = 2*L;   // slots 0..7
        gemm_nt<<<dim3(16, (M+63)/64), 256, 0, stream>>>(cur, lw + (size_t)s0*1024*512,
            lbi + s0*1024, lbh + s0*1024, xg_f, M, 1024, 512);
        gemm_nt<<<dim3(16, (M+63)/64), 256, 0, stream>>>(cur, lw + (size_t)(s0+1)*1024*512,
            lbi + (s0+1)*1024, lbh + (s0+1)*1024, xg_b, M, 1024, 512);
        lstm_scan<<<dim3(16,2), 256, 0, stream>>>(xg_f, xg_b,
            whhT + (size_t)s0*262144, whhT + (size_t)(s0+1)*262144, nxt, T);
        float* tmp = cur; cur = nxt; nxt = tmp;
    }
    // cur = final seq [16][61][512]

    // ---- enc projection ----
    gemm_nt<<<dim3(4, (M+63)/64), 256, 0, stream>>>(cur, encW, encB, nullptr, encb, M, 256, 512);

    // ---- decoder ----
    decoder_kernel<<<16, 512, 0, stream>>>(cur, encb, dpwT, dpb, vw, wihT, whh2T,
                                           dbih, dbhh, dwT, dnb, outp, T);
}

// Round 2
// 10566.055 us; speedup vs baseline: 2.6867x; 2.6867x over previous
//
#include <hip/hip_runtime.h>
#include <math.h>

__device__ __forceinline__ float sigmf(float x){ return 1.f/(1.f+expf(-x)); }

// ---------------- simple fused conv (kept for L0, Cin=1) ----------------
template<int KW, int PKH, int PKW>
__launch_bounds__(64)
__global__ void conv_pool(const float* __restrict__ in, const float* __restrict__ wgt,
                          const float* __restrict__ bias, float* __restrict__ out,
                          int Cin, int H, int W, int Cout,
                          int pad, int Hp, int Wp, int psh, int psw)
{
    extern __shared__ float sw[];
    const int tid = threadIdx.x;
    const int bco = blockIdx.z;
    const int co  = bco % Cout;
    const int nw  = Cin*KW*KW;
    {
        const float* wsrc = wgt + (size_t)co*nw;
        for (int i = tid; i < nw; i += 64) sw[i] = wsrc[i];
    }
    __syncthreads();
    const int wp = blockIdx.x*64 + tid;
    if (wp >= Wp) return;
    const int hp = blockIdx.y;
    const int b  = bco / Cout;
    constexpr int PH = PKH + KW - 1;
    constexpr int PW = PKW + KW - 1;
    const int y0 = hp*psh - pad;
    const int x0 = wp*psw - pad;
    int yo[PH]; bool ym[PH];
#pragma unroll
    for (int py=0; py<PH; ++py){ int y=y0+py; ym[py]=(y>=0)&&(y<H); yo[py]=y*W; }
    int xo[PW]; bool xm[PW];
#pragma unroll
    for (int px=0; px<PW; ++px){ int x=x0+px; xm[px]=(x>=0)&&(x<W); xo[px]=x; }
    float acc[PKH][PKW];
#pragma unroll
    for (int i=0;i<PKH;++i)
#pragma unroll
        for (int j=0;j<PKW;++j) acc[i][j]=0.f;

    const float* ip = in + (size_t)b*Cin*H*W;
    for (int ci=0; ci<Cin; ++ci, ip += (size_t)H*W) {
        float patch[PH][PW];
#pragma unroll
        for (int py=0; py<PH; ++py)
#pragma unroll
            for (int px=0; px<PW; ++px)
                patch[py][px] = (ym[py]&&xm[px]) ? ip[yo[py]+xo[px]] : 0.f;
        const float* wr = sw + ci*KW*KW;
#pragma unroll
        for (int ky=0; ky<KW; ++ky)
#pragma unroll
            for (int kx=0; kx<KW; ++kx) {
                float wv = wr[ky*KW+kx];
#pragma unroll
                for (int ph=0; ph<PKH; ++ph)
#pragma unroll
                    for (int pw2=0; pw2<PKW; ++pw2)
                        acc[ph][pw2] = fmaf(patch[ph+ky][pw2+kx], wv, acc[ph][pw2]);
            }
    }
    const float bv = bias[co];
    float m = -1e30f;
#pragma unroll
    for (int ph=0; ph<PKH; ++ph)
#pragma unroll
        for (int pw2=0; pw2<PKW; ++pw2) m = fmaxf(m, acc[ph][pw2]+bv);
    m = fmaxf(m, 0.f);
    out[((size_t)bco*Hp + hp)*Wp + wp] = m;
}

// ---------------- tiled conv: 32 co/block, LDS input staging, scalar weights ----------------
// 256 threads = 64 lanes (wp groups) x 4 waves (co groups of COT each)
template<int KW, int PKH, int PKW, int WPT, int COT, int PSW, int CICH>
__launch_bounds__(256)
__global__ void conv_tile(const float* __restrict__ in, const float* __restrict__ wgt,
                          const float* __restrict__ bias, float* __restrict__ out,
                          int Cin, int H, int W, int Cout, int pad, int Hp, int Wp, int psh)
{
    constexpr int PH  = PKH + KW - 1;                   // patch rows
    constexpr int PWD = (WPT-1)*PSW + PKW + KW - 1;     // patch cols per thread
    constexpr int WPB = 64*WPT;                         // wp per block
    constexpr int XW  = (WPB-1)*PSW + (PKW + KW - 1);   // staged row width
    __shared__ float tile[CICH][PH][XW];

    const int tid  = threadIdx.x;
    const int lane = tid & 63;
    const int cog  = __builtin_amdgcn_readfirstlane(tid >> 6);
    const int wp0  = blockIdx.x * WPB;
    const int hp   = blockIdx.y;
    const int nCoT = Cout / (COT*4);
    const int b    = blockIdx.z / nCoT;
    const int cot  = blockIdx.z % nCoT;
    const int co0  = cot*(COT*4) + cog*COT;
    const int y0   = hp*psh - pad;
    const int xb   = wp0*PSW - pad;

    float acc[COT][WPT][PKH][PKW];
#pragma unroll
    for (int c=0;c<COT;++c)
#pragma unroll
        for (int s=0;s<WPT;++s)
#pragma unroll
            for (int i=0;i<PKH;++i)
#pragma unroll
                for (int j=0;j<PKW;++j) acc[c][s][i][j]=0.f;

    const float*  inb    = in + (size_t)b*Cin*H*W;
    const size_t  costep = (size_t)Cin*KW*KW;
    const float*  wb     = wgt + (size_t)co0*costep;

    for (int ci0 = 0; ci0 < Cin; ci0 += CICH) {
        __syncthreads();
        constexpr int TOT = CICH*PH*XW;
        for (int idx = tid; idx < TOT; idx += 256) {
            int x  = idx % XW;
            int t2 = idx / XW;
            int r  = t2 % PH;
            int cc = t2 / PH;
            int y  = y0 + r;
            int xg = xb + x;
            float v = 0.f;
            if (y >= 0 && y < H && xg >= 0 && xg < W)
                v = inb[((size_t)(ci0+cc))*H*W + (size_t)y*W + xg];
            tile[cc][r][x] = v;
        }
        __syncthreads();
#pragma unroll
        for (int cc = 0; cc < CICH; ++cc) {
            const int ci = ci0 + cc;
            float p[PH][PWD];
#pragma unroll
            for (int r=0;r<PH;++r)
#pragma unroll
                for (int xx=0;xx<PWD;++xx)
                    p[r][xx] = tile[cc][r][lane*(WPT*PSW) + xx];
            const float* wrow = wb + (size_t)ci*(KW*KW);
#pragma unroll
            for (int c=0;c<COT;++c) {
#pragma unroll
                for (int ky=0;ky<KW;++ky)
#pragma unroll
                    for (int kx=0;kx<KW;++kx) {
                        float wv = wrow[c*costep + ky*KW + kx];   // wave-uniform -> s_load
#pragma unroll
                        for (int s=0;s<WPT;++s)
#pragma unroll
                            for (int i=0;i<PKH;++i)
#pragma unroll
                                for (int j=0;j<PKW;++j)
                                    acc[c][s][i][j] = fmaf(p[i+ky][s*PSW + j + kx], wv, acc[c][s][i][j]);
                    }
            }
        }
    }
#pragma unroll
    for (int c=0;c<COT;++c) {
        float bv = bias[co0 + c];
#pragma unroll
        for (int s=0;s<WPT;++s) {
            int wp = wp0 + lane*WPT + s;
            if (wp < Wp) {
                float m = -1e30f;
#pragma unroll
                for (int i=0;i<PKH;++i)
#pragma unroll
                    for (int j=0;j<PKW;++j) m = fmaxf(m, acc[c][s][i][j] + bv);
                m = fmaxf(m, 0.f);
                out[(((size_t)b*Cout + (co0+c))*Hp + hp)*Wp + wp] = m;
            }
        }
    }
}

// ---------------- fp32 GEMM: C[M,N] = A[M,K] * B[N,K]^T (+bias1+bias2) ----------------
__launch_bounds__(256)
__global__ void gemm_nt(const float* __restrict__ A, const float* __restrict__ Bm,
                        const float* __restrict__ bias1, const float* __restrict__ bias2,
                        float* __restrict__ C, int M, int N, int K)
{
    __shared__ float As[16][68];
    __shared__ float Bs[16][68];
    const int tid = threadIdx.x;
    const int tx = tid & 15, ty = tid >> 4;
    const int row0 = blockIdx.y*64, col0 = blockIdx.x*64;
    float acc[4][4] = {};
    for (int k0 = 0; k0 < K; k0 += 16) {
#pragma unroll
        for (int i = 0; i < 4; ++i) {
            int e  = tid + i*256;
            int r  = e >> 4, kk = e & 15;
            int gr = row0 + r, gk = k0 + kk;
            As[kk][r] = (gr < M) ? A[(size_t)gr*K + gk] : 0.f;
            int gc = col0 + r;
            Bs[kk][r] = (gc < N) ? Bm[(size_t)gc*K + gk] : 0.f;
        }
        __syncthreads();
#pragma unroll
        for (int kk = 0; kk < 16; ++kk) {
            float av[4], bv[4];
#pragma unroll
            for (int i=0;i<4;++i) av[i] = As[kk][ty*4+i];
#pragma unroll
            for (int j=0;j<4;++j) bv[j] = Bs[kk][tx*4+j];
#pragma unroll
            for (int i=0;i<4;++i)
#pragma unroll
                for (int j=0;j<4;++j) acc[i][j] = fmaf(av[i], bv[j], acc[i][j]);
        }
        __syncthreads();
    }
#pragma unroll
    for (int i=0;i<4;++i)
#pragma unroll
        for (int j=0;j<4;++j) {
            int r = row0 + ty*4 + i, cc = col0 + tx*4 + j;
            if (r < M && cc < N) {
                float v = acc[i][j];
                if (bias1) v += bias1[cc];
                if (bias2) v += bias2[cc];
                C[(size_t)r*N + cc] = v;
            }
        }
}

// ---------------- transposes / relayouts ----------------
__global__ void transpose2d(const float* __restrict__ in, float* __restrict__ out, int R, int C)
{
    int idx = blockIdx.x*256 + threadIdx.x;
    if (idx >= R*C) return;
    int r = idx / C, c = idx % C;
    out[(size_t)c*R + r] = in[idx];
}

// lstm whh [8][1024 g][256 k] -> [8][256 k][256 j][4 gate]
__global__ void transpose_whh4(const float* __restrict__ in, float* __restrict__ out)
{
    int idx = blockIdx.x*256 + threadIdx.x;
    if (idx >= 8*1024*256) return;
    int l = idx / 262144, rem = idx % 262144;
    int g = rem >> 8, k = rem & 255;
    int j = g & 255, gate = g >> 8;
    out[(size_t)l*262144 + ((size_t)k*256 + j)*4 + gate] = in[idx];
}

// decoder W [2048 rows = gate*512+j][512 k] -> [512 k][512 j][4 gate]
__global__ void transpose_w4(const float* __restrict__ in, float* __restrict__ out)
{
    int idx = blockIdx.x*256 + threadIdx.x;
    if (idx >= 2048*512) return;
    int row = idx >> 9, k = idx & 511;
    int gate = row >> 9, j = row & 511;
    out[((size_t)k*512 + j)*4 + gate] = in[idx];
}

// conv7 out [16][512][61] -> [16][61][512]
__global__ void transpose_c7(const float* __restrict__ in, float* __restrict__ out)
{
    int idx = blockIdx.x*256 + threadIdx.x;
    if (idx >= 16*512*61) return;
    int b = idx / (512*61), rem = idx % (512*61);
    int c = rem / 61, t = rem % 61;
    out[((size_t)b*61 + t)*512 + c] = in[idx];
}

// ---------------- LSTM scan v2: 1024 threads, 4-way K split ----------------
__launch_bounds__(1024)
__global__ void lstm_scan2(const float* __restrict__ xgf, const float* __restrict__ xgb,
                           const float* __restrict__ w4f, const float* __restrict__ w4b,
                           float* __restrict__ hout, int T)
{
    __shared__ float hs[256];
    __shared__ float part[4][256][4];
    const int b = blockIdx.x, dir = blockIdx.y;
    const int tid = threadIdx.x;
    const int j = tid & 255, ks = tid >> 8;
    const float* xg = dir ? xgb : xgf;
    const float4* w4 = (const float4*)(dir ? w4b : w4f);   // [256 k][256 j]
    float c = 0.f;
    if (ks == 0) hs[j] = 0.f;
    __syncthreads();
    float* outp = hout + dir*256 + j;
    for (int s = 0; s < T; ++s) {
        int t = dir ? (T-1-s) : s;
        float a0=0.f,a1=0.f,a2=0.f,a3=0.f;
        const float4* wp = w4 + (size_t)(ks*64)*256 + j;
#pragma unroll 8
        for (int kk = 0; kk < 64; ++kk) {
            float hv = hs[ks*64 + kk];
            float4 w = wp[(size_t)kk*256];
            a0 = fmaf(hv, w.x, a0); a1 = fmaf(hv, w.y, a1);
            a2 = fmaf(hv, w.z, a2); a3 = fmaf(hv, w.w, a3);
        }
        part[ks][j][0]=a0; part[ks][j][1]=a1; part[ks][j][2]=a2; part[ks][j][3]=a3;
        __syncthreads();
        if (ks == 0) {
            const float* xr = xg + ((size_t)b*T + t)*1024;
            float gi = xr[j]     + part[0][j][0]+part[1][j][0]+part[2][j][0]+part[3][j][0];
            float gf = xr[256+j] + part[0][j][1]+part[1][j][1]+part[2][j][1]+part[3][j][1];
            float gg = xr[512+j] + part[0][j][2]+part[1][j][2]+part[2][j][2]+part[3][j][2];
            float go = xr[768+j] + part[0][j][3]+part[1][j][3]+part[2][j][3]+part[3][j][3];
            c = sigmf(gf)*c + sigmf(gi)*tanhf(gg);
            float h = sigmf(go)*tanhf(c);
            hs[j] = h;
            outp[((size_t)b*T + t)*512] = h;
        }
        __syncthreads();
    }
}

// ---------------- decoder: batched per-step kernels ----------------
__global__ void zero_hc(float* __restrict__ h, float* __restrict__ c)
{
    int i = blockIdx.x*256 + threadIdx.x;
    if (i < 16*512) { h[i] = 0.f; c[i] = 0.f; }
}

__launch_bounds__(256)
__global__ void dec_att(const float* __restrict__ h, const float* __restrict__ seq,
                        const float* __restrict__ enc, const float* __restrict__ dpwT,
                        const float* __restrict__ dpb, const float* __restrict__ vw,
                        float* __restrict__ ctx, int T)
{
    __shared__ float hsm[512], dec[256], sc[64];
    const int b = blockIdx.x, tid = threadIdx.x;
    hsm[tid]     = h[b*512 + tid];
    hsm[256+tid] = h[b*512 + 256 + tid];
    __syncthreads();
    float s = dpb[tid];
    for (int k = 0; k < 512; ++k) s = fmaf(hsm[k], dpwT[(size_t)k*256 + tid], s);
    dec[tid] = s;
    __syncthreads();
    {
        int t = tid >> 2, sub = tid & 3;
        float p = 0.f;
        if (t < T) {
            const float* er = enc + ((size_t)b*T + t)*256 + sub*64;
            const float* dc = dec + sub*64;
            const float* vv = vw + sub*64;
            for (int a = 0; a < 64; ++a) p = fmaf(tanhf(er[a] + dc[a]), vv[a], p);
        }
        p += __shfl_xor(p, 1, 4); p += __shfl_xor(p, 2, 4);
        if (t < T && sub == 0) sc[t] = p;
    }
    __syncthreads();
    if (tid < 64) {
        float v = (tid < T) ? sc[tid] : -1e30f;
        float m = v;
        for (int o = 1; o < 64; o <<= 1) m = fmaxf(m, __shfl_xor(m, o, 64));
        float e = (tid < T) ? expf(v - m) : 0.f;
        float ssum = e;
        for (int o = 1; o < 64; o <<= 1) ssum += __shfl_xor(ssum, o, 64);
        if (tid < T) sc[tid] = e / ssum;
    }
    __syncthreads();
#pragma unroll
    for (int half = 0; half < 2; ++half) {
        int col = tid + half*256;
        float acc = 0.f;
        const float* sr = seq + (size_t)b*T*512 + col;
        for (int t = 0; t < T; ++t) acc = fmaf(sc[t], sr[(size_t)t*512], acc);
        ctx[b*512 + col] = acc;
    }
}

// gates partials: grid (4 jt, 4 ks), 256 thr; gpart[ks][16 b][512 j *4 gate]
__launch_bounds__(256)
__global__ void gates_part(const float* __restrict__ ctx, const float* __restrict__ h,
                           const float* __restrict__ wi4, const float* __restrict__ wh4,
                           float* __restrict__ gpart)
{
    __shared__ float xs[16][128], hsh[16][128];
    const int jt = blockIdx.x, ks = blockIdx.y;
    const int tid = threadIdx.x;
    const int jl = tid & 127, bh = tid >> 7;
    const int j = jt*128 + jl;
    const int k0 = ks*128;
    for (int idx = tid; idx < 2048; idx += 256) {
        int bb = idx >> 7, kk = idx & 127;
        xs[bb][kk]  = ctx[bb*512 + k0 + kk];
        hsh[bb][kk] = h[bb*512 + k0 + kk];
    }
    __syncthreads();
    float acc[8][4];
#pragma unroll
    for (int bi=0;bi<8;++bi)
#pragma unroll
        for (int g=0;g<4;++g) acc[bi][g]=0.f;
    const float4* wip = (const float4*)wi4 + (size_t)k0*512 + j;
    const float4* whp = (const float4*)wh4 + (size_t)k0*512 + j;
#pragma unroll 2
    for (int kk = 0; kk < 128; ++kk) {
        float4 wa = wip[(size_t)kk*512];
        float4 wb = whp[(size_t)kk*512];
#pragma unroll
        for (int bi = 0; bi < 8; ++bi) {
            int bb = bh*8 + bi;
            float xv = xs[bb][kk], hv = hsh[bb][kk];
            acc[bi][0] = fmaf(xv, wa.x, fmaf(hv, wb.x, acc[bi][0]));
            acc[bi][1] = fmaf(xv, wa.y, fmaf(hv, wb.y, acc[bi][1]));
            acc[bi][2] = fmaf(xv, wa.z, fmaf(hv, wb.z, acc[bi][2]));
            acc[bi][3] = fmaf(xv, wa.w, fmaf(hv, wb.w, acc[bi][3]));
        }
    }
    float* gp = gpart + (size_t)ks*16*2048;
#pragma unroll
    for (int bi = 0; bi < 8; ++bi)
#pragma unroll
        for (int g = 0; g < 4; ++g)
            gp[(size_t)(bh*8+bi)*2048 + j*4 + g] = acc[bi][g];
}

__launch_bounds__(512)
__global__ void cell_dense(float* __restrict__ h, float* __restrict__ c,
                           const float* __restrict__ gpart,
                           const float* __restrict__ bih, const float* __restrict__ bhh,
                           const float* __restrict__ dwT, const float* __restrict__ dnb,
                           float* __restrict__ out)
{
    __shared__ float hsh[512];
    const int b = blockIdx.x, j = threadIdx.x;
    float gi = bih[j]        + bhh[j];
    float gf = bih[512+j]    + bhh[512+j];
    float gg = bih[1024+j]   + bhh[1024+j];
    float go = bih[1536+j]   + bhh[1536+j];
#pragma unroll
    for (int ks = 0; ks < 4; ++ks) {
        float4 gp = *(const float4*)(gpart + (size_t)ks*16*2048 + (size_t)b*2048 + j*4);
        gi += gp.x; gf += gp.y; gg += gp.z; go += gp.w;
    }
    float cn = sigmf(gf)*c[b*512+j] + sigmf(gi)*tanhf(gg);
    float hn = sigmf(go)*tanhf(cn);
    c[b*512+j] = cn; h[b*512+j] = hn; hsh[j] = hn;
    __syncthreads();
    int o = j >> 2, sub = j & 3;
    float p = 0.f;
    if (o < 99) {
        const float* hk = hsh + sub*128;
        const float* wk = dwT + (size_t)sub*128*99 + o;
        for (int k = 0; k < 128; ++k) p = fmaf(hk[k], wk[(size_t)k*99], p);
    }
    p += __shfl_xor(p, 1, 4); p += __shfl_xor(p, 2, 4);
    if (o < 99 && sub == 0) out[b*99 + o] = p + dnb[o];
}

// ---------------- launch ----------------
extern "C" void kernel_launch(void* const* d_in, const int* in_sizes, int n_in,
                              void* d_out, int out_size, void* d_ws, size_t ws_size,
                              hipStream_t stream)
{
    (void)in_sizes; (void)n_in; (void)out_size; (void)ws_size;
    const float* x = (const float*)d_in[0];
    const float* convw[7]; const float* convb[7];
    for (int i = 0; i < 7; ++i) { convw[i] = (const float*)d_in[1+2*i]; convb[i] = (const float*)d_in[2+2*i]; }
    const float* lw   = (const float*)d_in[15];
    const float* lr   = (const float*)d_in[16];
    const float* lbi  = (const float*)d_in[17];
    const float* lbh  = (const float*)d_in[18];
    const float* encW = (const float*)d_in[19];
    const float* encB = (const float*)d_in[20];
    const float* dpw  = (const float*)d_in[21];
    const float* dpb  = (const float*)d_in[22];
    const float* vw   = (const float*)d_in[23];
    const float* dwih = (const float*)d_in[24];
    const float* dwhh = (const float*)d_in[25];
    const float* dbih = (const float*)d_in[26];
    const float* dbhh = (const float*)d_in[27];
    const float* dnw  = (const float*)d_in[28];
    const float* dnb  = (const float*)d_in[29];
    float* outp = (float*)d_out;

    float* ws    = (float*)d_ws;
    float* bufA  = ws;                        // 16,777,216 floats
    float* bufB  = ws + 16777216;             //  8,388,608 floats
    float* seq_x = bufB;                      // 499,712
    float* seq_y = bufB + 499712;
    float* xg_f  = bufB + 999424;             // 999,424
    float* xg_b  = bufB + 1998848;
    float* whhT4 = bufB + 2998272;            // 2,097,152
    float* encb  = bufB + 5095424;            // 249,856
    float* dpwT  = bufB + 5345280;            // 131,072
    float* wihT4 = bufB + 5476352;            // 1,048,576
    float* whh2T4= bufB + 6524928;            // 1,048,576
    float* dwT   = bufB + 7573504;            // 50,688
    float* hbuf  = bufB + 7624192;            // 8,192
    float* cbuf  = bufB + 7632384;            // 8,192
    float* ctxb  = bufB + 7640576;            // 8,192
    float* gpart = bufB + 7648768;            // 131,072 (end 7,779,840)

    // ---- convs ----
    // L0 (Cin=1): simple kernel. in 1x128x512 -> out 64x64x256
    conv_pool<3,2,2><<<dim3(4,64,16*64), 64, 9*sizeof(float), stream>>>(
        x, convw[0], convb[0], bufA, 1,128,512,64, 1, 64,256, 2,2);
    // L1: 64->128, in 64x256 -> pooled 32x128 (psw=2)
    conv_tile<3,2,2,2,8,2,2><<<dim3(1,32,16*4), 256, 0, stream>>>(
        bufA, convw[1], convb[1], bufB, 64,64,256,128, 1, 32,128, 2);
    // L2: 128->256, in 32x128 -> pooled 16x127 (psw=1)
    conv_tile<3,2,2,2,8,1,2><<<dim3(1,16,16*8), 256, 0, stream>>>(
        bufB, convw[2], convb[2], bufA, 128,32,128,256, 1, 16,127, 2);
    // L3: 256->512, in 16x127 -> pooled 8x126 (psw=1)
    conv_tile<3,2,2,2,8,1,2><<<dim3(1,8,16*16), 256, 0, stream>>>(
        bufA, convw[3], convb[3], bufB, 256,16,127,512, 1, 8,126, 2);
    // L4: 512->512, in 8x126 -> pooled 4x63 (psw=2)
    conv_tile<3,2,2,1,8,2,2><<<dim3(1,4,16*16), 256, 0, stream>>>(
        bufB, convw[4], convb[4], bufA, 512,8,126,512, 1, 4,63, 2);
    // L5: 512->512, in 4x63 -> pooled 2x62 (psw=1)
    conv_tile<3,2,2,1,8,1,2><<<dim3(1,2,16*16), 256, 0, stream>>>(
        bufA, convw[5], convb[5], bufB, 512,4,63,512, 1, 2,62, 2);
    // L6: 512->512 k2 pad0, in 2x62 -> 1x61, no pool
    conv_tile<2,1,1,1,8,1,8><<<dim3(1,1,16*16), 256, 0, stream>>>(
        bufB, convw[6], convb[6], bufA, 512,2,62,512, 0, 1,61, 1);

    // ---- reshape to [B,T,512] ----
    transpose_c7<<<(16*512*61 + 255)/256, 256, 0, stream>>>(bufA, seq_x);

    // ---- weight relayouts ----
    transpose_whh4<<<(8*1024*256 + 255)/256, 256, 0, stream>>>(lr, whhT4);
    transpose2d<<<(256*512 + 255)/256, 256, 0, stream>>>(dpw, dpwT, 256, 512);
    transpose_w4<<<(2048*512 + 255)/256, 256, 0, stream>>>(dwih, wihT4);
    transpose_w4<<<(2048*512 + 255)/256, 256, 0, stream>>>(dwhh, whh2T4);
    transpose2d<<<(99*512 + 255)/256, 256, 0, stream>>>(dnw, dwT, 99, 512);

    // ---- 4 BiLSTM layers ----
    const int T = 61, M = 16*T;
    float* cur = seq_x; float* nxt = seq_y;
    for (int L = 0; L < 4; ++L) {
        int s0 = 2*L;
        gemm_nt<<<dim3(16, (M+63)/64), 256, 0, stream>>>(cur, lw + (size_t)s0*1024*512,
            lbi + s0*1024, lbh + s0*1024, xg_f, M, 1024, 512);
        gemm_nt<<<dim3(16, (M+63)/64), 256, 0, stream>>>(cur, lw + (size_t)(s0+1)*1024*512,
            lbi + (s0+1)*1024, lbh + (s0+1)*1024, xg_b, M, 1024, 512);
        lstm_scan2<<<dim3(16,2), 1024, 0, stream>>>(xg_f, xg_b,
            whhT4 + (size_t)s0*262144, whhT4 + (size_t)(s0+1)*262144, nxt, T);
        float* tmp = cur; cur = nxt; nxt = tmp;
    }
    // cur = final seq [16][61][512]

    // ---- enc projection ----
    gemm_nt<<<dim3(4, (M+63)/64), 256, 0, stream>>>(cur, encW, encB, nullptr, encb, M, 256, 512);

    // ---- decoder: 25 batched steps ----
    zero_hc<<<32, 256, 0, stream>>>(hbuf, cbuf);
    for (int step = 0; step < 25; ++step) {
        dec_att<<<16, 256, 0, stream>>>(hbuf, cur, encb, dpwT, dpb, vw, ctxb, T);
        gates_part<<<dim3(4,4), 256, 0, stream>>>(ctxb, hbuf, wihT4, whh2T4, gpart);
        cell_dense<<<16, 512, 0, stream>>>(hbuf, cbuf, gpart, dbih, dbhh, dwT, dnb,
                                           outp + (size_t)step*16*99);
    }
}

// Round 4
// 5370.999 us; speedup vs baseline: 5.2853x; 1.9672x over previous
//
#include <hip/hip_runtime.h>
#include <math.h>

typedef short bf16x8 __attribute__((ext_vector_type(8)));
typedef float f32x4  __attribute__((ext_vector_type(4)));

__device__ __forceinline__ float sigmf(float x){ return 1.f/(1.f+expf(-x)); }
__device__ __forceinline__ short f2bf(float f){
    unsigned u = __float_as_uint(f);
    u = (u + 0x7FFFu + ((u>>16)&1u)) >> 16;
    return (short)u;
}
__device__ __forceinline__ float bf2f(short s){
    return __uint_as_float(((unsigned)(unsigned short)s) << 16);
}

// ---------------- weight split into MFMA A-fragment order ----------------
// layout: idx = ((kk*nCoQ + coQ)*KST + ks)*64 + lane ; 8 bf16 per idx
// value[e] = W[co=coQ*16+(l&15)][ci=ks*32+(l>>4)*8+e][ky=kk/KW][kx=kk%KW]
__global__ void wsplit(const float* __restrict__ w, short* __restrict__ whi, short* __restrict__ wlo,
                       int Cout, int Cin, int KW, int total)
{
    int idx = blockIdx.x*256 + threadIdx.x;
    if (idx >= total) return;
    int l = idx & 63; int t = idx >> 6;
    int KST = Cin >> 5;
    int ks = t % KST; t /= KST;
    int nCoQ = Cout >> 4;
    int coQ = t % nCoQ; int kk = t / nCoQ;
    int ky = kk / KW, kx = kk % KW;
    int co = coQ*16 + (l & 15);
    int ci = ks*32 + (l >> 4)*8;
    bf16x8 h, lo;
#pragma unroll
    for (int e = 0; e < 8; ++e) {
        float wv = w[(((size_t)co*Cin + ci + e)*KW + ky)*KW + kx];
        short hb = f2bf(wv);
        h[e] = hb;
        lo[e] = f2bf(wv - bf2f(hb));
    }
    ((bf16x8*)whi)[idx] = h;
    ((bf16x8*)wlo)[idx] = lo;
}

// ---------------- MFMA conv + bias + relu + maxpool ----------------
// block: 128 co x 64 pre-pool x x PKH pre-pool rows; 4 waves = 2(co) x 2(x)
// input fp32 channel-last [b][y][x][ci]  (FUSE0: compute L0 conv+pool on the fly from raw x)
// output fp32 channel-last [b][hp][px][co]
template<int KW, int PKH, int PKW, int PSW, int PAD, bool FUSE0>
__launch_bounds__(256)
__global__ void conv_mfma(const float* __restrict__ in, const short* __restrict__ wm,
                          const float* __restrict__ bias, float* __restrict__ out,
                          int Cin, int H, int W, int Cout, int Hp, int Wp, int Wel,
                          const float* __restrict__ w0, const float* __restrict__ b0)
{
    constexpr int TAPS = KW*KW;
    constexpr int SR   = PKH + KW - 1;       // staged rows
    constexpr int XT   = 64;
    constexpr int XTH  = 67;                 // padded staged width (odd*16B stride)
    constexpr int POB  = (XT - PKW)/PSW + 1; // pooled outputs per tile
    __shared__ union {
        short s[2][16][XTH][8];              // [plane][srow*4+kslot][x][8ci]
        float y[64][132];                    // pre-pool (row-maxed) tile for pooling
    } u;
    __shared__ float w0s[640];

    const int tid  = threadIdx.x;
    const int lane = tid & 63;
    const int wid  = tid >> 6;
    const int l15  = lane & 15, l4 = lane >> 4;
    const int nCoT = Cout >> 7;
    const int b    = blockIdx.z / nCoT;
    const int ct   = blockIdx.z % nCoT;
    const int co_blk = ct << 7;
    const int hp   = blockIdx.y;
    const int px0  = blockIdx.x * POB;
    const int x0   = px0 * PSW;
    const int y0   = hp * PKH;               // pool stride in H == PKH for all layers
    const int cow  = wid >> 1;
    const int xw   = (wid & 1) * 32;
    const int KST  = Cin >> 5;
    const int nCoQ = Cout >> 4;

    if constexpr (FUSE0) {
        for (int i = tid; i < 640; i += 256) w0s[i] = (i < 576) ? w0[i] : b0[i-576];
    }

    f32x4 acc[4][2][PKH];
#pragma unroll
    for (int c = 0; c < 4; ++c)
#pragma unroll
        for (int xf = 0; xf < 2; ++xf)
#pragma unroll
            for (int r = 0; r < PKH; ++r) acc[c][xf][r] = (f32x4){0.f,0.f,0.f,0.f};

    const float* inb = FUSE0 ? (in + (size_t)b*128*512) : (in + (size_t)b*H*W*Cin);

    for (int ci0 = 0; ci0 < Cin; ci0 += 32) {
        __syncthreads();
        constexpr int ITEMS = SR*XTH*4;
        for (int it = tid; it < ITEMS; it += 256) {
            int kslot = it & 3;
            int x  = (it >> 2) % XTH;
            int r  = (it >> 2) / XTH;
            int y  = y0 - PAD + r;
            int xg = x0 - PAD + x;
            float v[8];
            if constexpr (FUSE0) {
                if (y >= 0 && y < H && xg >= 0 && xg < W) {
                    float xin[4][4];
                    int iy0 = 2*y - 1, ix0 = 2*xg - 1;
#pragma unroll
                    for (int dy = 0; dy < 4; ++dy) {
                        int iy = iy0 + dy;
                        bool oky = (iy >= 0) && (iy < 128);
#pragma unroll
                        for (int dx = 0; dx < 4; ++dx) {
                            int ix = ix0 + dx;
                            xin[dy][dx] = (oky && ix >= 0 && ix < 512) ? inb[(size_t)iy*512 + ix] : 0.f;
                        }
                    }
#pragma unroll
                    for (int c = 0; c < 8; ++c) {
                        int co = ci0 + kslot*8 + c;
                        const float* w9 = &w0s[co*9];
                        float p00=0.f,p01=0.f,p10=0.f,p11=0.f;
#pragma unroll
                        for (int ky = 0; ky < 3; ++ky)
#pragma unroll
                            for (int kx = 0; kx < 3; ++kx) {
                                float wv = w9[ky*3+kx];
                                p00 = fmaf(xin[ky  ][kx  ], wv, p00);
                                p01 = fmaf(xin[ky  ][kx+1], wv, p01);
                                p10 = fmaf(xin[ky+1][kx  ], wv, p10);
                                p11 = fmaf(xin[ky+1][kx+1], wv, p11);
                            }
                        float m = fmaxf(fmaxf(p00,p01), fmaxf(p10,p11)) + w0s[576+co];
                        v[c] = fmaxf(m, 0.f);
                    }
                } else {
#pragma unroll
                    for (int c = 0; c < 8; ++c) v[c] = 0.f;
                }
            } else {
                if (y >= 0 && y < H && xg >= 0 && xg < W) {
                    const float* p = inb + ((size_t)y*W + xg)*Cin + ci0 + kslot*8;
                    float4 a = *(const float4*)p;
                    float4 bq = *(const float4*)(p+4);
                    v[0]=a.x; v[1]=a.y; v[2]=a.z; v[3]=a.w;
                    v[4]=bq.x; v[5]=bq.y; v[6]=bq.z; v[7]=bq.w;
                } else {
#pragma unroll
                    for (int c = 0; c < 8; ++c) v[c] = 0.f;
                }
            }
            bf16x8 h8, l8;
#pragma unroll
            for (int c = 0; c < 8; ++c) {
                short hb = f2bf(v[c]);
                h8[c] = hb;
                l8[c] = f2bf(v[c] - bf2f(hb));
            }
            *(bf16x8*)&u.s[0][r*4+kslot][x][0] = h8;
            *(bf16x8*)&u.s[1][r*4+kslot][x][0] = l8;
        }
        __syncthreads();

        const int ks = ci0 >> 5;
        for (int kk = 0; kk < TAPS; ++kk) {
            const int ky = kk / KW, kx = kk % KW;
            bf16x8 ah[4], al[4];
            const size_t abase = (((size_t)kk*nCoQ + (co_blk>>4) + cow*4)*KST + ks)*512 + lane*8;
            const size_t cstr  = (size_t)KST*512;
#pragma unroll
            for (int c = 0; c < 4; ++c) {
                ah[c] = *(const bf16x8*)(wm + abase + c*cstr);
                al[c] = *(const bf16x8*)(wm + Wel + abase + c*cstr);
            }
#pragma unroll
            for (int r = 0; r < PKH; ++r) {
                const int sr = r + ky;
                bf16x8 bh[2], bl[2];
#pragma unroll
                for (int xf = 0; xf < 2; ++xf) {
                    int xcol = xw + xf*16 + l15 + kx;
                    bh[xf] = *(const bf16x8*)&u.s[0][sr*4 + l4][xcol][0];
                    bl[xf] = *(const bf16x8*)&u.s[1][sr*4 + l4][xcol][0];
                }
#pragma unroll
                for (int c = 0; c < 4; ++c)
#pragma unroll
                    for (int xf = 0; xf < 2; ++xf) {
                        acc[c][xf][r] = __builtin_amdgcn_mfma_f32_16x16x32_bf16(ah[c], bh[xf], acc[c][xf][r], 0,0,0);
                        acc[c][xf][r] = __builtin_amdgcn_mfma_f32_16x16x32_bf16(ah[c], bl[xf], acc[c][xf][r], 0,0,0);
                        acc[c][xf][r] = __builtin_amdgcn_mfma_f32_16x16x32_bf16(al[c], bh[xf], acc[c][xf][r], 0,0,0);
                    }
            }
        }
    }

    // ---- epilogue: bias + row-max -> LDS, then pool x + relu + store ----
    __syncthreads();
#pragma unroll
    for (int c = 0; c < 4; ++c) {
        int co_l = cow*64 + c*16 + l4*4;
        float4 b4 = *(const float4*)&bias[co_blk + co_l];
#pragma unroll
        for (int xf = 0; xf < 2; ++xf) {
            f32x4 v = acc[c][xf][0];
            if (PKH == 2) {
                f32x4 v1 = acc[c][xf][1];
                v[0]=fmaxf(v[0],v1[0]); v[1]=fmaxf(v[1],v1[1]);
                v[2]=fmaxf(v[2],v1[2]); v[3]=fmaxf(v[3],v1[3]);
            }
            v[0]+=b4.x; v[1]+=b4.y; v[2]+=b4.z; v[3]+=b4.w;
            int x = xw + xf*16 + l15;
            *(f32x4*)&u.y[x][co_l] = v;
        }
    }
    __syncthreads();
    for (int i = tid; i < POB*128; i += 256) {
        int co = i & 127, p = i >> 7;
        int x = p * PSW;
        float v = u.y[x][co];
        if (PKW == 2) v = fmaxf(v, u.y[x+1][co]);
        v = fmaxf(v, 0.f);
        int px = px0 + p;
        if (px < Wp)
            out[(((size_t)b*Hp + hp)*Wp + px)*Cout + co_blk + co] = v;
    }
}

// ---------------- fp32 GEMM: C[M,N] = A[M,K] * B[N,K]^T (+bias1+bias2) ----------------
__launch_bounds__(256)
__global__ void gemm_nt(const float* __restrict__ A, const float* __restrict__ Bm,
                        const float* __restrict__ bias1, const float* __restrict__ bias2,
                        float* __restrict__ C, int M, int N, int K)
{
    __shared__ float As[16][68];
    __shared__ float Bs[16][68];
    const int tid = threadIdx.x;
    const int tx = tid & 15, ty = tid >> 4;
    const int row0 = blockIdx.y*64, col0 = blockIdx.x*64;
    float acc[4][4] = {};
    for (int k0 = 0; k0 < K; k0 += 16) {
#pragma unroll
        for (int i = 0; i < 4; ++i) {
            int e  = tid + i*256;
            int r  = e >> 4, kk = e & 15;
            int gr = row0 + r, gk = k0 + kk;
            As[kk][r] = (gr < M) ? A[(size_t)gr*K + gk] : 0.f;
            int gc = col0 + r;
            Bs[kk][r] = (gc < N) ? Bm[(size_t)gc*K + gk] : 0.f;
        }
        __syncthreads();
#pragma unroll
        for (int kk = 0; kk < 16; ++kk) {
            float av[4], bv[4];
#pragma unroll
            for (int i=0;i<4;++i) av[i] = As[kk][ty*4+i];
#pragma unroll
            for (int j=0;j<4;++j) bv[j] = Bs[kk][tx*4+j];
#pragma unroll
            for (int i=0;i<4;++i)
#pragma unroll
                for (int j=0;j<4;++j) acc[i][j] = fmaf(av[i], bv[j], acc[i][j]);
        }
        __syncthreads();
    }
#pragma unroll
    for (int i=0;i<4;++i)
#pragma unroll
        for (int j=0;j<4;++j) {
            int r = row0 + ty*4 + i, cc = col0 + tx*4 + j;
            if (r < M && cc < N) {
                float v = acc[i][j];
                if (bias1) v += bias1[cc];
                if (bias2) v += bias2[cc];
                C[(size_t)r*N + cc] = v;
            }
        }
}

// ---------------- transposes / relayouts ----------------
__global__ void transpose2d(const float* __restrict__ in, float* __restrict__ out, int R, int C)
{
    int idx = blockIdx.x*256 + threadIdx.x;
    if (idx >= R*C) return;
    int r = idx / C, c = idx % C;
    out[(size_t)c*R + r] = in[idx];
}

// lstm whh [8][1024 g][256 k] -> [8][256 k][256 j][4 gate]
__global__ void transpose_whh4(const float* __restrict__ in, float* __restrict__ out)
{
    int idx = blockIdx.x*256 + threadIdx.x;
    if (idx >= 8*1024*256) return;
    int l = idx / 262144, rem = idx % 262144;
    int g = rem >> 8, k = rem & 255;
    int j = g & 255, gate = g >> 8;
    out[(size_t)l*262144 + ((size_t)k*256 + j)*4 + gate] = in[idx];
}

// decoder W [2048 rows = gate*512+j][512 k] -> [512 k][512 j][4 gate]
__global__ void transpose_w4(const float* __restrict__ in, float* __restrict__ out)
{
    int idx = blockIdx.x*256 + threadIdx.x;
    if (idx >= 2048*512) return;
    int row = idx >> 9, k = idx & 511;
    int gate = row >> 9, j = row & 511;
    out[((size_t)k*512 + j)*4 + gate] = in[idx];
}

// ---------------- LSTM scan: 1024 threads, 4-way K split ----------------
__launch_bounds__(1024)
__global__ void lstm_scan2(const float* __restrict__ xgf, const float* __restrict__ xgb,
                           const float* __restrict__ w4f, const float* __restrict__ w4b,
                           float* __restrict__ hout, int T)
{
    __shared__ float hs[256];
    __shared__ float part[4][256][4];
    const int b = blockIdx.x, dir = blockIdx.y;
    const int tid = threadIdx.x;
    const int j = tid & 255, ks = tid >> 8;
    const float* xg = dir ? xgb : xgf;
    const float4* w4 = (const float4*)(dir ? w4b : w4f);
    float c = 0.f;
    if (ks == 0) hs[j] = 0.f;
    __syncthreads();
    float* outp = hout + dir*256 + j;
    for (int s = 0; s < T; ++s) {
        int t = dir ? (T-1-s) : s;
        float a0=0.f,a1=0.f,a2=0.f,a3=0.f;
        const float4* wp = w4 + (size_t)(ks*64)*256 + j;
#pragma unroll 8
        for (int kk = 0; kk < 64; ++kk) {
            float hv = hs[ks*64 + kk];
            float4 w = wp[(size_t)kk*256];
            a0 = fmaf(hv, w.x, a0); a1 = fmaf(hv, w.y, a1);
            a2 = fmaf(hv, w.z, a2); a3 = fmaf(hv, w.w, a3);
        }
        part[ks][j][0]=a0; part[ks][j][1]=a1; part[ks][j][2]=a2; part[ks][j][3]=a3;
        __syncthreads();
        if (ks == 0) {
            const float* xr = xg + ((size_t)b*T + t)*1024;
            float gi = xr[j]     + part[0][j][0]+part[1][j][0]+part[2][j][0]+part[3][j][0];
            float gf = xr[256+j] + part[0][j][1]+part[1][j][1]+part[2][j][1]+part[3][j][1];
            float gg = xr[512+j] + part[0][j][2]+part[1][j][2]+part[2][j][2]+part[3][j][2];
            float go = xr[768+j] + part[0][j][3]+part[1][j][3]+part[2][j][3]+part[3][j][3];
            c = sigmf(gf)*c + sigmf(gi)*tanhf(gg);
            float h = sigmf(go)*tanhf(c);
            hs[j] = h;
            outp[((size_t)b*T + t)*512] = h;
        }
        __syncthreads();
    }
}

// ---------------- decoder: batched per-step kernels ----------------
__global__ void zero_hc(float* __restrict__ h, float* __restrict__ c)
{
    int i = blockIdx.x*256 + threadIdx.x;
    if (i < 16*512) { h[i] = 0.f; c[i] = 0.f; }
}

__launch_bounds__(256)
__global__ void dec_att(const float* __restrict__ h, const float* __restrict__ seq,
                        const float* __restrict__ enc, const float* __restrict__ dpwT,
                        const float* __restrict__ dpb, const float* __restrict__ vw,
                        float* __restrict__ ctx, int T)
{
    __shared__ float hsm[512], dec[256], sc[64];
    const int b = blockIdx.x, tid = threadIdx.x;
    hsm[tid]     = h[b*512 + tid];
    hsm[256+tid] = h[b*512 + 256 + tid];
    __syncthreads();
    float s = dpb[tid];
    for (int k = 0; k < 512; ++k) s = fmaf(hsm[k], dpwT[(size_t)k*256 + tid], s);
    dec[tid] = s;
    __syncthreads();
    {
        int t = tid >> 2, sub = tid & 3;
        float p = 0.f;
        if (t < T) {
            const float* er = enc + ((size_t)b*T + t)*256 + sub*64;
            const float* dc = dec + sub*64;
            const float* vv = vw + sub*64;
            for (int a = 0; a < 64; ++a) p = fmaf(tanhf(er[a] + dc[a]), vv[a], p);
        }
        p += __shfl_xor(p, 1, 4); p += __shfl_xor(p, 2, 4);
        if (t < T && sub == 0) sc[t] = p;
    }
    __syncthreads();
    if (tid < 64) {
        float v = (tid < T) ? sc[tid] : -1e30f;
        float m = v;
        for (int o = 1; o < 64; o <<= 1) m = fmaxf(m, __shfl_xor(m, o, 64));
        float e = (tid < T) ? expf(v - m) : 0.f;
        float ssum = e;
        for (int o = 1; o < 64; o <<= 1) ssum += __shfl_xor(ssum, o, 64);
        if (tid < T) sc[tid] = e / ssum;
    }
    __syncthreads();
#pragma unroll
    for (int half = 0; half < 2; ++half) {
        int col = tid + half*256;
        float acc = 0.f;
        const float* sr = seq + (size_t)b*T*512 + col;
        for (int t = 0; t < T; ++t) acc = fmaf(sc[t], sr[(size_t)t*512], acc);
        ctx[b*512 + col] = acc;
    }
}

__launch_bounds__(256)
__global__ void gates_part(const float* __restrict__ ctx, const float* __restrict__ h,
                           const float* __restrict__ wi4, const float* __restrict__ wh4,
                           float* __restrict__ gpart)
{
    __shared__ float xs[16][128], hsh[16][128];
    const int jt = blockIdx.x, ks = blockIdx.y;
    const int tid = threadIdx.x;
    const int jl = tid & 127, bh = tid >> 7;
    const int j = jt*128 + jl;
    const int k0 = ks*128;
    for (int idx = tid; idx < 2048; idx += 256) {
        int bb = idx >> 7, kk = idx & 127;
        xs[bb][kk]  = ctx[bb*512 + k0 + kk];
        hsh[bb][kk] = h[bb*512 + k0 + kk];
    }
    __syncthreads();
    float acc[8][4];
#pragma unroll
    for (int bi=0;bi<8;++bi)
#pragma unroll
        for (int g=0;g<4;++g) acc[bi][g]=0.f;
    const float4* wip = (const float4*)wi4 + (size_t)k0*512 + j;
    const float4* whp = (const float4*)wh4 + (size_t)k0*512 + j;
#pragma unroll 2
    for (int kk = 0; kk < 128; ++kk) {
        float4 wa = wip[(size_t)kk*512];
        float4 wb = whp[(size_t)kk*512];
#pragma unroll
        for (int bi = 0; bi < 8; ++bi) {
            int bb = bh*8 + bi;
            float xv = xs[bb][kk], hv = hsh[bb][kk];
            acc[bi][0] = fmaf(xv, wa.x, fmaf(hv, wb.x, acc[bi][0]));
            acc[bi][1] = fmaf(xv, wa.y, fmaf(hv, wb.y, acc[bi][1]));
            acc[bi][2] = fmaf(xv, wa.z, fmaf(hv, wb.z, acc[bi][2]));
            acc[bi][3] = fmaf(xv, wa.w, fmaf(hv, wb.w, acc[bi][3]));
        }
    }
    float* gp = gpart + (size_t)ks*16*2048;
#pragma unroll
    for (int bi = 0; bi < 8; ++bi)
#pragma unroll
        for (int g = 0; g < 4; ++g)
            gp[(size_t)(bh*8+bi)*2048 + j*4 + g] = acc[bi][g];
}

__launch_bounds__(512)
__global__ void cell_dense(float* __restrict__ h, float* __restrict__ c,
                           const float* __restrict__ gpart,
                           const float* __restrict__ bih, const float* __restrict__ bhh,
                           const float* __restrict__ dwT, const float* __restrict__ dnb,
                           float* __restrict__ out)
{
    __shared__ float hsh[512];
    const int b = blockIdx.x, j = threadIdx.x;
    float gi = bih[j]        + bhh[j];
    float gf = bih[512+j]    + bhh[512+j];
    float gg = bih[1024+j]   + bhh[1024+j];
    float go = bih[1536+j]   + bhh[1536+j];
#pragma unroll
    for (int ks = 0; ks < 4; ++ks) {
        float4 gp = *(const float4*)(gpart + (size_t)ks*16*2048 + (size_t)b*2048 + j*4);
        gi += gp.x; gf += gp.y; gg += gp.z; go += gp.w;
    }
    float cn = sigmf(gf)*c[b*512+j] + sigmf(gi)*tanhf(gg);
    float hn = sigmf(go)*tanhf(cn);
    c[b*512+j] = cn; h[b*512+j] = hn; hsh[j] = hn;
    __syncthreads();
    int o = j >> 2, sub = j & 3;
    float p = 0.f;
    if (o < 99) {
        const float* hk = hsh + sub*128;
        const float* wk = dwT + (size_t)sub*128*99 + o;
        for (int k = 0; k < 128; ++k) p = fmaf(hk[k], wk[(size_t)k*99], p);
    }
    p += __shfl_xor(p, 1, 4); p += __shfl_xor(p, 2, 4);
    if (o < 99 && sub == 0) out[b*99 + o] = p + dnb[o];
}

// ---------------- launch ----------------
extern "C" void kernel_launch(void* const* d_in, const int* in_sizes, int n_in,
                              void* d_out, int out_size, void* d_ws, size_t ws_size,
                              hipStream_t stream)
{
    (void)in_sizes; (void)n_in; (void)out_size; (void)ws_size;
    const float* x = (const float*)d_in[0];
    const float* convw[7]; const float* convb[7];
    for (int i = 0; i < 7; ++i) { convw[i] = (const float*)d_in[1+2*i]; convb[i] = (const float*)d_in[2+2*i]; }
    const float* lw   = (const float*)d_in[15];
    const float* lr   = (const float*)d_in[16];
    const float* lbi  = (const float*)d_in[17];
    const float* lbh  = (const float*)d_in[18];
    const float* encW = (const float*)d_in[19];
    const float* encB = (const float*)d_in[20];
    const float* dpw  = (const float*)d_in[21];
    const float* dpb  = (const float*)d_in[22];
    const float* vw   = (const float*)d_in[23];
    const float* dwih = (const float*)d_in[24];
    const float* dwhh = (const float*)d_in[25];
    const float* dbih = (const float*)d_in[26];
    const float* dbhh = (const float*)d_in[27];
    const float* dnw  = (const float*)d_in[28];
    const float* dnb  = (const float*)d_in[29];
    float* outp = (float*)d_out;

    float* ws    = (float*)d_ws;
    float* bufA  = ws;                       // 8,388,608
    float* bufB  = ws + 8388608;             // 8,388,608
    float* wscr  = ws + 16777216;            // 2,359,296 (weight split scratch)
    float* S0    = ws + 19136512;            // 499,712 (seq ping)
    float* SY    = ws + 19636224;            // 499,712 (seq pong)
    float* xg_f  = ws + 20135936;            // 999,424
    float* xg_b  = ws + 21135360;            // 999,424
    float* whhT4 = ws + 22134784;            // 2,097,152
    float* encb  = ws + 24231936;            // 249,856
    float* dpwT  = ws + 24481792;            // 131,072
    float* dwT   = ws + 24612864;            // 50,688
    float* hbuf  = ws + 24663552;            // 8,192
    float* cbuf  = ws + 24671744;            // 8,192
    float* ctxb  = ws + 24679936;            // 8,192
    float* gpart = ws + 24688128;            // 131,072 -> end 24,819,200
    float* wihT4 = bufA;                     // after convs
    float* whh2T4= bufB;                     // after convs

    short* whi = (short*)wscr;

    // ---- convs (L0 fused into L1) ----
    // L1: Cin=64(=L0 co), "input" H=64,W=256 (L0-pooled), Cout=128, pool s(2,2) -> 32x128
    {
        int Wel = 9*(128/16)*(64/32)*512;    // 73,728
        wsplit<<<(Wel/8+255)/256, 256, 0, stream>>>(convw[1], whi, whi+Wel, 128, 64, 3, Wel/8);
        conv_mfma<3,2,2,2,1,true><<<dim3(4,32,16), 256, 0, stream>>>(
            x, whi, convb[1], bufA, 64,64,256,128, 32,128, Wel, convw[0], convb[0]);
    }
    // L2: 128->256, in 32x128 -> 16x127 (psw=1)
    {
        int Wel = 9*(256/16)*(128/32)*512;   // 294,912
        wsplit<<<(Wel/8+255)/256, 256, 0, stream>>>(convw[2], whi, whi+Wel, 256, 128, 3, Wel/8);
        conv_mfma<3,2,2,1,1,false><<<dim3(3,16,32), 256, 0, stream>>>(
            bufA, whi, convb[2], bufB, 128,32,128,256, 16,127, Wel, nullptr, nullptr);
    }
    // L3: 256->512, in 16x127 -> 8x126 (psw=1)
    {
        int Wel = 9*(512/16)*(256/32)*512;   // 1,179,648
        wsplit<<<(Wel/8+255)/256, 256, 0, stream>>>(convw[3], whi, whi+Wel, 512, 256, 3, Wel/8);
        conv_mfma<3,2,2,1,1,false><<<dim3(2,8,64), 256, 0, stream>>>(
            bufB, whi, convb[3], bufA, 256,16,127,512, 8,126, Wel, nullptr, nullptr);
    }
    // L4: 512->512, in 8x126 -> 4x63 (psw=2)
    {
        int Wel = 9*(512/16)*(512/32)*512;   // 2,359,296
        wsplit<<<(Wel/8+255)/256, 256, 0, stream>>>(convw[4], whi, whi+Wel, 512, 512, 3, Wel/8);
        conv_mfma<3,2,2,2,1,false><<<dim3(2,4,64), 256, 0, stream>>>(
            bufA, whi, convb[4], bufB, 512,8,126,512, 4,63, Wel, nullptr, nullptr);
    }
    // L5: 512->512, in 4x63 -> 2x62 (psw=1)
    {
        int Wel = 9*(512/16)*(512/32)*512;
        wsplit<<<(Wel/8+255)/256, 256, 0, stream>>>(convw[5], whi, whi+Wel, 512, 512, 3, Wel/8);
        conv_mfma<3,2,2,1,1,false><<<dim3(1,2,64), 256, 0, stream>>>(
            bufB, whi, convb[5], bufA, 512,4,63,512, 2,62, Wel, nullptr, nullptr);
    }
    // L6: 512->512 k2 pad0, in 2x62 -> 1x61, no pool; writes seq [16][61][512] directly
    {
        int Wel = 4*(512/16)*(512/32)*512;   // 1,048,576
        wsplit<<<(Wel/8+255)/256, 256, 0, stream>>>(convw[6], whi, whi+Wel, 512, 512, 2, Wel/8);
        conv_mfma<2,1,1,1,0,false><<<dim3(1,1,64), 256, 0, stream>>>(
            bufA, whi, convb[6], S0, 512,2,62,512, 1,61, Wel, nullptr, nullptr);
    }

    // ---- weight relayouts (bufA/bufB free now) ----
    transpose_whh4<<<(8*1024*256 + 255)/256, 256, 0, stream>>>(lr, whhT4);
    transpose2d<<<(256*512 + 255)/256, 256, 0, stream>>>(dpw, dpwT, 256, 512);
    transpose_w4<<<(2048*512 + 255)/256, 256, 0, stream>>>(dwih, wihT4);
    transpose_w4<<<(2048*512 + 255)/256, 256, 0, stream>>>(dwhh, whh2T4);
    transpose2d<<<(99*512 + 255)/256, 256, 0, stream>>>(dnw, dwT, 99, 512);

    // ---- 4 BiLSTM layers ----
    const int T = 61, M = 16*T;
    float* cur = S0; float* nxt = SY;
    for (int L = 0; L < 4; ++L) {
        int s0 = 2*L;
        gemm_nt<<<dim3(16, (M+63)/64), 256, 0, stream>>>(cur, lw + (size_t)s0*1024*512,
            lbi + s0*1024, lbh + s0*1024, xg_f, M, 1024, 512);
        gemm_nt<<<dim3(16, (M+63)/64), 256, 0, stream>>>(cur, lw + (size_t)(s0+1)*1024*512,
            lbi + (s0+1)*1024, lbh + (s0+1)*1024, xg_b, M, 1024, 512);
        lstm_scan2<<<dim3(16,2), 1024, 0, stream>>>(xg_f, xg_b,
            whhT4 + (size_t)s0*262144, whhT4 + (size_t)(s0+1)*262144, nxt, T);
        float* tmp = cur; cur = nxt; nxt = tmp;
    }
    // cur = S0 = final seq [16][61][512]

    // ---- enc projection ----
    gemm_nt<<<dim3(4, (M+63)/64), 256, 0, stream>>>(cur, encW, encB, nullptr, encb, M, 256, 512);

    // ---- decoder: 25 batched steps ----
    zero_hc<<<32, 256, 0, stream>>>(hbuf, cbuf);
    for (int step = 0; step < 25; ++step) {
        dec_att<<<16, 256, 0, stream>>>(hbuf, cur, encb, dpwT, dpb, vw, ctxb, T);
        gates_part<<<dim3(4,4), 256, 0, stream>>>(ctxb, hbuf, wihT4, whh2T4, gpart);
        cell_dense<<<16, 512, 0, stream>>>(hbuf, cbuf, gpart, dbih, dbhh, dwT, dnb,
                                           outp + (size_t)step*16*99);
    }
}

// Round 5
// 5081.023 us; speedup vs baseline: 5.5869x; 1.0571x over previous
//
#include <hip/hip_runtime.h>
#include <math.h>

typedef short bf16x8 __attribute__((ext_vector_type(8)));
typedef short s16x4  __attribute__((ext_vector_type(4)));
typedef float f32x4  __attribute__((ext_vector_type(4)));

__device__ __forceinline__ float sigmf(float x){ return 1.f/(1.f+expf(-x)); }
__device__ __forceinline__ short f2bf(float f){
    unsigned u = __float_as_uint(f);
    u = (u + 0x7FFFu + ((u>>16)&1u)) >> 16;
    return (short)u;
}
__device__ __forceinline__ float bf2f(short s){
    return __uint_as_float(((unsigned)(unsigned short)s) << 16);
}

// ---------------- conv weight split into MFMA A-fragment order ----------------
// layout: idx = ((kk*nCoQ + coQ)*KST + ks)*64 + lane ; 8 bf16 per idx
__global__ void wsplit(const float* __restrict__ w, short* __restrict__ whi, short* __restrict__ wlo,
                       int Cout, int Cin, int KW, int total)
{
    int idx = blockIdx.x*256 + threadIdx.x;
    if (idx >= total) return;
    int l = idx & 63; int t = idx >> 6;
    int KST = Cin >> 5;
    int ks = t % KST; t /= KST;
    int nCoQ = Cout >> 4;
    int coQ = t % nCoQ; int kk = t / nCoQ;
    int ky = kk / KW, kx = kk % KW;
    int co = coQ*16 + (l & 15);
    int ci = ks*32 + (l >> 4)*8;
    bf16x8 h, lo;
#pragma unroll
    for (int e = 0; e < 8; ++e) {
        float wv = w[(((size_t)co*Cin + ci + e)*KW + ky)*KW + kx];
        short hb = f2bf(wv);
        h[e] = hb;
        lo[e] = f2bf(wv - bf2f(hb));
    }
    ((bf16x8*)whi)[idx] = h;
    ((bf16x8*)wlo)[idx] = lo;
}

// ---------------- lstm gate-weight split into fragment order ----------------
// per slot: [nQ(64)][kc(16)][lane(64)][8]; hi plane 524288 shorts, lo plane follows
__global__ void wsplit_g(const float* __restrict__ w, short* __restrict__ out)
{
    int slot = blockIdx.y;
    int i = blockIdx.x*256 + threadIdx.x;     // 0..65535
    int l = i & 63, t = i >> 6;
    int kc = t & 15, nQ = t >> 4;
    int n = nQ*16 + (l & 15);
    int k = kc*32 + (l >> 4)*8;
    const float* src = w + ((size_t)slot*1024 + n)*512 + k;
    bf16x8 h, lo;
#pragma unroll
    for (int e = 0; e < 8; ++e) {
        float wv = src[e];
        short hb = f2bf(wv);
        h[e] = hb;
        lo[e] = f2bf(wv - bf2f(hb));
    }
    short* o = out + (size_t)slot*1048576;
    ((bf16x8*)o)[i] = h;
    ((bf16x8*)(o + 524288))[i] = lo;
}

// ---------------- MFMA conv + bias + relu + maxpool ----------------
template<int KW, int PKH, int PKW, int PSW, int PAD, bool FUSE0>
__launch_bounds__(256)
__global__ void conv_mfma(const float* __restrict__ in, const short* __restrict__ wm,
                          const float* __restrict__ bias, float* __restrict__ out,
                          int Cin, int H, int W, int Cout, int Hp, int Wp, int Wel,
                          const float* __restrict__ w0, const float* __restrict__ b0)
{
    constexpr int TAPS = KW*KW;
    constexpr int SR   = PKH + KW - 1;
    constexpr int XT   = 64;
    constexpr int XTH  = 67;
    constexpr int POB  = (XT - PKW)/PSW + 1;
    __shared__ union {
        short s[2][16][XTH][8];
        float y[64][132];
    } u;
    __shared__ float w0s[640];

    const int tid  = threadIdx.x;
    const int lane = tid & 63;
    const int wid  = tid >> 6;
    const int l15  = lane & 15, l4 = lane >> 4;
    const int nCoT = Cout >> 7;
    const int b    = blockIdx.z / nCoT;
    const int ct   = blockIdx.z % nCoT;
    const int co_blk = ct << 7;
    const int hp   = blockIdx.y;
    const int px0  = blockIdx.x * POB;
    const int x0   = px0 * PSW;
    const int y0   = hp * PKH;
    const int cow  = wid >> 1;
    const int xw   = (wid & 1) * 32;
    const int KST  = Cin >> 5;
    const int nCoQ = Cout >> 4;

    if constexpr (FUSE0) {
        for (int i = tid; i < 640; i += 256) w0s[i] = (i < 576) ? w0[i] : b0[i-576];
    }

    f32x4 acc[4][2][PKH];
#pragma unroll
    for (int c = 0; c < 4; ++c)
#pragma unroll
        for (int xf = 0; xf < 2; ++xf)
#pragma unroll
            for (int r = 0; r < PKH; ++r) acc[c][xf][r] = (f32x4){0.f,0.f,0.f,0.f};

    const float* inb = FUSE0 ? (in + (size_t)b*128*512) : (in + (size_t)b*H*W*Cin);

    for (int ci0 = 0; ci0 < Cin; ci0 += 32) {
        __syncthreads();
        constexpr int ITEMS = SR*XTH*4;
        for (int it = tid; it < ITEMS; it += 256) {
            int kslot = it & 3;
            int x  = (it >> 2) % XTH;
            int r  = (it >> 2) / XTH;
            int y  = y0 - PAD + r;
            int xg = x0 - PAD + x;
            float v[8];
            if constexpr (FUSE0) {
                if (y >= 0 && y < H && xg >= 0 && xg < W) {
                    float xin[4][4];
                    int iy0 = 2*y - 1, ix0 = 2*xg - 1;
#pragma unroll
                    for (int dy = 0; dy < 4; ++dy) {
                        int iy = iy0 + dy;
                        bool oky = (iy >= 0) && (iy < 128);
#pragma unroll
                        for (int dx = 0; dx < 4; ++dx) {
                            int ix = ix0 + dx;
                            xin[dy][dx] = (oky && ix >= 0 && ix < 512) ? inb[(size_t)iy*512 + ix] : 0.f;
                        }
                    }
#pragma unroll
                    for (int c = 0; c < 8; ++c) {
                        int co = ci0 + kslot*8 + c;
                        const float* w9 = &w0s[co*9];
                        float p00=0.f,p01=0.f,p10=0.f,p11=0.f;
#pragma unroll
                        for (int ky = 0; ky < 3; ++ky)
#pragma unroll
                            for (int kx = 0; kx < 3; ++kx) {
                                float wv = w9[ky*3+kx];
                                p00 = fmaf(xin[ky  ][kx  ], wv, p00);
                                p01 = fmaf(xin[ky  ][kx+1], wv, p01);
                                p10 = fmaf(xin[ky+1][kx  ], wv, p10);
                                p11 = fmaf(xin[ky+1][kx+1], wv, p11);
                            }
                        float m = fmaxf(fmaxf(p00,p01), fmaxf(p10,p11)) + w0s[576+co];
                        v[c] = fmaxf(m, 0.f);
                    }
                } else {
#pragma unroll
                    for (int c = 0; c < 8; ++c) v[c] = 0.f;
                }
            } else {
                if (y >= 0 && y < H && xg >= 0 && xg < W) {
                    const float* p = inb + ((size_t)y*W + xg)*Cin + ci0 + kslot*8;
                    float4 a = *(const float4*)p;
                    float4 bq = *(const float4*)(p+4);
                    v[0]=a.x; v[1]=a.y; v[2]=a.z; v[3]=a.w;
                    v[4]=bq.x; v[5]=bq.y; v[6]=bq.z; v[7]=bq.w;
                } else {
#pragma unroll
                    for (int c = 0; c < 8; ++c) v[c] = 0.f;
                }
            }
            bf16x8 h8, l8;
#pragma unroll
            for (int c = 0; c < 8; ++c) {
                short hb = f2bf(v[c]);
                h8[c] = hb;
                l8[c] = f2bf(v[c] - bf2f(hb));
            }
            *(bf16x8*)&u.s[0][r*4+kslot][x][0] = h8;
            *(bf16x8*)&u.s[1][r*4+kslot][x][0] = l8;
        }
        __syncthreads();

        const int ks = ci0 >> 5;
        for (int kk = 0; kk < TAPS; ++kk) {
            const int ky = kk / KW, kx = kk % KW;
            bf16x8 ah[4], al[4];
            const size_t abase = (((size_t)kk*nCoQ + (co_blk>>4) + cow*4)*KST + ks)*512 + lane*8;
            const size_t cstr  = (size_t)KST*512;
#pragma unroll
            for (int c = 0; c < 4; ++c) {
                ah[c] = *(const bf16x8*)(wm + abase + c*cstr);
                al[c] = *(const bf16x8*)(wm + Wel + abase + c*cstr);
            }
#pragma unroll
            for (int r = 0; r < PKH; ++r) {
                const int sr = r + ky;
                bf16x8 bh[2], bl[2];
#pragma unroll
                for (int xf = 0; xf < 2; ++xf) {
                    int xcol = xw + xf*16 + l15 + kx;
                    bh[xf] = *(const bf16x8*)&u.s[0][sr*4 + l4][xcol][0];
                    bl[xf] = *(const bf16x8*)&u.s[1][sr*4 + l4][xcol][0];
                }
#pragma unroll
                for (int c = 0; c < 4; ++c)
#pragma unroll
                    for (int xf = 0; xf < 2; ++xf) {
                        acc[c][xf][r] = __builtin_amdgcn_mfma_f32_16x16x32_bf16(ah[c], bh[xf], acc[c][xf][r], 0,0,0);
                        acc[c][xf][r] = __builtin_amdgcn_mfma_f32_16x16x32_bf16(ah[c], bl[xf], acc[c][xf][r], 0,0,0);
                        acc[c][xf][r] = __builtin_amdgcn_mfma_f32_16x16x32_bf16(al[c], bh[xf], acc[c][xf][r], 0,0,0);
                    }
            }
        }
    }

    __syncthreads();
#pragma unroll
    for (int c = 0; c < 4; ++c) {
        int co_l = cow*64 + c*16 + l4*4;
        float4 b4 = *(const float4*)&bias[co_blk + co_l];
#pragma unroll
        for (int xf = 0; xf < 2; ++xf) {
            f32x4 v = acc[c][xf][0];
            if (PKH == 2) {
                f32x4 v1 = acc[c][xf][1];
                v[0]=fmaxf(v[0],v1[0]); v[1]=fmaxf(v[1],v1[1]);
                v[2]=fmaxf(v[2],v1[2]); v[3]=fmaxf(v[3],v1[3]);
            }
            v[0]+=b4.x; v[1]+=b4.y; v[2]+=b4.z; v[3]+=b4.w;
            int x = xw + xf*16 + l15;
            *(f32x4*)&u.y[x][co_l] = v;
        }
    }
    __syncthreads();
    for (int i = tid; i < POB*128; i += 256) {
        int co = i & 127, p = i >> 7;
        int x = p * PSW;
        float v = u.y[x][co];
        if (PKW == 2) v = fmaxf(v, u.y[x+1][co]);
        v = fmaxf(v, 0.f);
        int px = px0 + p;
        if (px < Wp)
            out[(((size_t)b*Hp + hp)*Wp + px)*Cout + co_blk + co] = v;
    }
}

// ---------------- MFMA split-bf16 gate GEMM: xg = A[M,512]*W[1024,512]^T + bi + bh ----------------
// grid: (Mtiles, 8, 2 slots); block 256 = 4 waves (cow = n-half, xw = m-half)
__launch_bounds__(256)
__global__ void gemm_mfma(const float* __restrict__ A, const short* __restrict__ wg,
                          const float* __restrict__ bi, const float* __restrict__ bh,
                          float* __restrict__ Cf, float* __restrict__ Cb,
                          int M, int s0)
{
    __shared__ short sa[2][4][64][8];   // [plane][mgroup][kslot*16+m15][8]
    const int tid = threadIdx.x;
    const int lane = tid & 63;
    const int wid = tid >> 6;
    const int l15 = lane & 15, l4 = lane >> 4;
    const int cow = wid >> 1;
    const int xw  = wid & 1;
    const int m0 = blockIdx.x * 64;
    const int n0 = blockIdx.y * 128;
    const int slot = s0 + blockIdx.z;
    const short* whi = wg + (size_t)slot * 1048576;
    const short* wlo = whi + 524288;
    float* C = blockIdx.z ? Cb : Cf;
    const float* b1 = bi + slot*1024;
    const float* b2 = bh + slot*1024;

    const int mg  = wid;
    const int pos = tid & 63;
    const int sm  = mg*16 + (pos & 15);
    const int skl = pos >> 4;
    const int gm  = m0 + sm;
    const int nQb = blockIdx.y*8 + cow*4;

    f32x4 acc[4][2];
#pragma unroll
    for (int c = 0; c < 4; ++c)
#pragma unroll
        for (int xf = 0; xf < 2; ++xf) acc[c][xf] = (f32x4){0.f,0.f,0.f,0.f};

    for (int kc = 0; kc < 16; ++kc) {
        __syncthreads();
        {
            float v[8];
            if (gm < M) {
                const float* ap = A + (size_t)gm*512 + kc*32 + skl*8;
                float4 q0 = *(const float4*)ap;
                float4 q1 = *(const float4*)(ap+4);
                v[0]=q0.x; v[1]=q0.y; v[2]=q0.z; v[3]=q0.w;
                v[4]=q1.x; v[5]=q1.y; v[6]=q1.z; v[7]=q1.w;
            } else {
#pragma unroll
                for (int e = 0; e < 8; ++e) v[e] = 0.f;
            }
            bf16x8 h8, l8;
#pragma unroll
            for (int e = 0; e < 8; ++e) {
                short hb = f2bf(v[e]);
                h8[e] = hb;
                l8[e] = f2bf(v[e] - bf2f(hb));
            }
            *(bf16x8*)&sa[0][mg][pos][0] = h8;
            *(bf16x8*)&sa[1][mg][pos][0] = l8;
        }
        __syncthreads();

        bf16x8 ah[4], al[4];
#pragma unroll
        for (int c = 0; c < 4; ++c) {
            size_t off = (((size_t)(nQb + c)*16 + kc)*64 + lane)*8;
            ah[c] = *(const bf16x8*)(whi + off);
            al[c] = *(const bf16x8*)(wlo + off);
        }
        bf16x8 bhv[2], blv[2];
#pragma unroll
        for (int xf = 0; xf < 2; ++xf) {
            bhv[xf] = *(const bf16x8*)&sa[0][xw*2+xf][lane][0];
            blv[xf] = *(const bf16x8*)&sa[1][xw*2+xf][lane][0];
        }
#pragma unroll
        for (int c = 0; c < 4; ++c)
#pragma unroll
            for (int xf = 0; xf < 2; ++xf) {
                acc[c][xf] = __builtin_amdgcn_mfma_f32_16x16x32_bf16(ah[c], bhv[xf], acc[c][xf], 0,0,0);
                acc[c][xf] = __builtin_amdgcn_mfma_f32_16x16x32_bf16(ah[c], blv[xf], acc[c][xf], 0,0,0);
                acc[c][xf] = __builtin_amdgcn_mfma_f32_16x16x32_bf16(al[c], bhv[xf], acc[c][xf], 0,0,0);
            }
    }

#pragma unroll
    for (int c = 0; c < 4; ++c) {
        int n = n0 + cow*64 + c*16 + l4*4;
        float4 bb1 = *(const float4*)&b1[n];
        float4 bb2 = *(const float4*)&b2[n];
#pragma unroll
        for (int xf = 0; xf < 2; ++xf) {
            int m = m0 + xw*32 + xf*16 + l15;
            if (m < M) {
                f32x4 a = acc[c][xf];
                float4 o;
                o.x = a[0] + bb1.x + bb2.x;
                o.y = a[1] + bb1.y + bb2.y;
                o.z = a[2] + bb1.z + bb2.z;
                o.w = a[3] + bb1.w + bb2.w;
                *(float4*)&C[(size_t)m*1024 + n] = o;
            }
        }
    }
}

// ---------------- fp32 GEMM (enc projection): C[M,N] = A[M,K]*B[N,K]^T (+bias) ----------------
__launch_bounds__(256)
__global__ void gemm_nt(const float* __restrict__ A, const float* __restrict__ Bm,
                        const float* __restrict__ bias1, const float* __restrict__ bias2,
                        float* __restrict__ C, int M, int N, int K)
{
    __shared__ float As[16][68];
    __shared__ float Bs[16][68];
    const int tid = threadIdx.x;
    const int tx = tid & 15, ty = tid >> 4;
    const int row0 = blockIdx.y*64, col0 = blockIdx.x*64;
    float acc[4][4] = {};
    for (int k0 = 0; k0 < K; k0 += 16) {
#pragma unroll
        for (int i = 0; i < 4; ++i) {
            int e  = tid + i*256;
            int r  = e >> 4, kk = e & 15;
            int gr = row0 + r, gk = k0 + kk;
            As[kk][r] = (gr < M) ? A[(size_t)gr*K + gk] : 0.f;
            int gc = col0 + r;
            Bs[kk][r] = (gc < N) ? Bm[(size_t)gc*K + gk] : 0.f;
        }
        __syncthreads();
#pragma unroll
        for (int kk = 0; kk < 16; ++kk) {
            float av[4], bv[4];
#pragma unroll
            for (int i=0;i<4;++i) av[i] = As[kk][ty*4+i];
#pragma unroll
            for (int j=0;j<4;++j) bv[j] = Bs[kk][tx*4+j];
#pragma unroll
            for (int i=0;i<4;++i)
#pragma unroll
                for (int j=0;j<4;++j) acc[i][j] = fmaf(av[i], bv[j], acc[i][j]);
        }
        __syncthreads();
    }
#pragma unroll
    for (int i=0;i<4;++i)
#pragma unroll
        for (int j=0;j<4;++j) {
            int r = row0 + ty*4 + i, cc = col0 + tx*4 + j;
            if (r < M && cc < N) {
                float v = acc[i][j];
                if (bias1) v += bias1[cc];
                if (bias2) v += bias2[cc];
                C[(size_t)r*N + cc] = v;
            }
        }
}

// ---------------- transposes / relayouts ----------------
__global__ void transpose2d(const float* __restrict__ in, float* __restrict__ out, int R, int C)
{
    int idx = blockIdx.x*256 + threadIdx.x;
    if (idx >= R*C) return;
    int r = idx / C, c = idx % C;
    out[(size_t)c*R + r] = in[idx];
}

// lstm whh [8][1024 g][256 k] -> bf16 [8][256 k][256 j][4 gate]
__global__ void pack_whh_bf16(const float* __restrict__ in, short* __restrict__ out)
{
    int idx = blockIdx.x*256 + threadIdx.x;
    if (idx >= 8*1024*256) return;
    int l = idx / 262144, rem = idx % 262144;
    int g = rem >> 8, k = rem & 255;
    int j = g & 255, gate = g >> 8;
    out[(size_t)l*262144 + ((size_t)k*256 + j)*4 + gate] = f2bf(in[idx]);
}

// decoder W [2048 rows = gate*512+j][512 k] -> [512 k][512 j][4 gate]
__global__ void transpose_w4(const float* __restrict__ in, float* __restrict__ out)
{
    int idx = blockIdx.x*256 + threadIdx.x;
    if (idx >= 2048*512) return;
    int row = idx >> 9, k = idx & 511;
    int gate = row >> 9, j = row & 511;
    out[((size_t)k*512 + j)*4 + gate] = in[idx];
}

// ---------------- LSTM scan: 1024 threads, 4-way K split, bf16 weights ----------------
__launch_bounds__(1024)
__global__ void lstm_scan3(const float* __restrict__ xgf, const float* __restrict__ xgb,
                           const short* __restrict__ wBf, const short* __restrict__ wBb,
                           float* __restrict__ hout, int T)
{
    __shared__ float hs[256];
    __shared__ float part[4][256][4];
    const int b = blockIdx.x, dir = blockIdx.y;
    const int tid = threadIdx.x;
    const int j = tid & 255, ks = tid >> 8;
    const float* xg = dir ? xgb : xgf;
    const s16x4* w4 = (const s16x4*)(dir ? wBb : wBf);   // [256 k][256 j] of short4
    float c = 0.f;
    if (ks == 0) hs[j] = 0.f;
    __syncthreads();
    float* outp = hout + dir*256 + j;
    for (int s = 0; s < T; ++s) {
        int t = dir ? (T-1-s) : s;
        float xi=0.f, xf_=0.f, xg_=0.f, xo=0.f;
        if (ks == 0) {
            const float* xr = xg + ((size_t)b*T + t)*1024;
            xi = xr[j]; xf_ = xr[256+j]; xg_ = xr[512+j]; xo = xr[768+j];
        }
        float a0=0.f,a1=0.f,a2=0.f,a3=0.f;
        const s16x4* wp = w4 + (size_t)(ks*64)*256 + j;
#pragma unroll 16
        for (int kk = 0; kk < 64; ++kk) {
            float hv = hs[ks*64 + kk];
            s16x4 w = wp[(size_t)kk*256];
            a0 = fmaf(hv, bf2f(w[0]), a0);
            a1 = fmaf(hv, bf2f(w[1]), a1);
            a2 = fmaf(hv, bf2f(w[2]), a2);
            a3 = fmaf(hv, bf2f(w[3]), a3);
        }
        part[ks][j][0]=a0; part[ks][j][1]=a1; part[ks][j][2]=a2; part[ks][j][3]=a3;
        __syncthreads();
        if (ks == 0) {
            float gi = xi  + part[0][j][0]+part[1][j][0]+part[2][j][0]+part[3][j][0];
            float gf = xf_ + part[0][j][1]+part[1][j][1]+part[2][j][1]+part[3][j][1];
            float gg = xg_ + part[0][j][2]+part[1][j][2]+part[2][j][2]+part[3][j][2];
            float go = xo  + part[0][j][3]+part[1][j][3]+part[2][j][3]+part[3][j][3];
            c = sigmf(gf)*c + sigmf(gi)*tanhf(gg);
            float h = sigmf(go)*tanhf(c);
            hs[j] = h;
            outp[((size_t)b*T + t)*512] = h;
        }
        __syncthreads();
    }
}

// ---------------- decoder: batched per-step kernels ----------------
__global__ void zero_hc(float* __restrict__ h, float* __restrict__ c)
{
    int i = blockIdx.x*256 + threadIdx.x;
    if (i < 16*512) { h[i] = 0.f; c[i] = 0.f; }
}

__launch_bounds__(256)
__global__ void dec_att(const float* __restrict__ h, const float* __restrict__ seq,
                        const float* __restrict__ enc, const float* __restrict__ dpwT,
                        const float* __restrict__ dpb, const float* __restrict__ vw,
                        float* __restrict__ ctx, int T)
{
    __shared__ float hsm[512], dec[256], sc[64];
    const int b = blockIdx.x, tid = threadIdx.x;
    hsm[tid]     = h[b*512 + tid];
    hsm[256+tid] = h[b*512 + 256 + tid];
    __syncthreads();
    float s = dpb[tid];
    for (int k = 0; k < 512; ++k) s = fmaf(hsm[k], dpwT[(size_t)k*256 + tid], s);
    dec[tid] = s;
    __syncthreads();
    {
        int t = tid >> 2, sub = tid & 3;
        float p = 0.f;
        if (t < T) {
            const float* er = enc + ((size_t)b*T + t)*256 + sub*64;
            const float* dc = dec + sub*64;
            const float* vv = vw + sub*64;
            for (int a = 0; a < 64; ++a) p = fmaf(tanhf(er[a] + dc[a]), vv[a], p);
        }
        p += __shfl_xor(p, 1, 4); p += __shfl_xor(p, 2, 4);
        if (t < T && sub == 0) sc[t] = p;
    }
    __syncthreads();
    if (tid < 64) {
        float v = (tid < T) ? sc[tid] : -1e30f;
        float m = v;
        for (int o = 1; o < 64; o <<= 1) m = fmaxf(m, __shfl_xor(m, o, 64));
        float e = (tid < T) ? expf(v - m) : 0.f;
        float ssum = e;
        for (int o = 1; o < 64; o <<= 1) ssum += __shfl_xor(ssum, o, 64);
        if (tid < T) sc[tid] = e / ssum;
    }
    __syncthreads();
#pragma unroll
    for (int half = 0; half < 2; ++half) {
        int col = tid + half*256;
        float acc = 0.f;
        const float* sr = seq + (size_t)b*T*512 + col;
        for (int t = 0; t < T; ++t) acc = fmaf(sc[t], sr[(size_t)t*512], acc);
        ctx[b*512 + col] = acc;
    }
}

__launch_bounds__(256)
__global__ void gates_part(const float* __restrict__ ctx, const float* __restrict__ h,
                           const float* __restrict__ wi4, const float* __restrict__ wh4,
                           float* __restrict__ gpart)
{
    __shared__ float xs[16][128], hsh[16][128];
    const int jt = blockIdx.x, ks = blockIdx.y;
    const int tid = threadIdx.x;
    const int jl = tid & 127, bh = tid >> 7;
    const int j = jt*128 + jl;
    const int k0 = ks*128;
    for (int idx = tid; idx < 2048; idx += 256) {
        int bb = idx >> 7, kk = idx & 127;
        xs[bb][kk]  = ctx[bb*512 + k0 + kk];
        hsh[bb][kk] = h[bb*512 + k0 + kk];
    }
    __syncthreads();
    float acc[8][4];
#pragma unroll
    for (int bi=0;bi<8;++bi)
#pragma unroll
        for (int g=0;g<4;++g) acc[bi][g]=0.f;
    const float4* wip = (const float4*)wi4 + (size_t)k0*512 + j;
    const float4* whp = (const float4*)wh4 + (size_t)k0*512 + j;
#pragma unroll 2
    for (int kk = 0; kk < 128; ++kk) {
        float4 wa = wip[(size_t)kk*512];
        float4 wb = whp[(size_t)kk*512];
#pragma unroll
        for (int bi = 0; bi < 8; ++bi) {
            int bb = bh*8 + bi;
            float xv = xs[bb][kk], hv = hsh[bb][kk];
            acc[bi][0] = fmaf(xv, wa.x, fmaf(hv, wb.x, acc[bi][0]));
            acc[bi][1] = fmaf(xv, wa.y, fmaf(hv, wb.y, acc[bi][1]));
            acc[bi][2] = fmaf(xv, wa.z, fmaf(hv, wb.z, acc[bi][2]));
            acc[bi][3] = fmaf(xv, wa.w, fmaf(hv, wb.w, acc[bi][3]));
        }
    }
    float* gp = gpart + (size_t)ks*16*2048;
#pragma unroll
    for (int bi = 0; bi < 8; ++bi)
#pragma unroll
        for (int g = 0; g < 4; ++g)
            gp[(size_t)(bh*8+bi)*2048 + j*4 + g] = acc[bi][g];
}

__launch_bounds__(512)
__global__ void cell_dense(float* __restrict__ h, float* __restrict__ c,
                           const float* __restrict__ gpart,
                           const float* __restrict__ bih, const float* __restrict__ bhh,
                           const float* __restrict__ dwT, const float* __restrict__ dnb,
                           float* __restrict__ out)
{
    __shared__ float hsh[512];
    const int b = blockIdx.x, j = threadIdx.x;
    float gi = bih[j]        + bhh[j];
    float gf = bih[512+j]    + bhh[512+j];
    float gg = bih[1024+j]   + bhh[1024+j];
    float go = bih[1536+j]   + bhh[1536+j];
#pragma unroll
    for (int ks = 0; ks < 4; ++ks) {
        float4 gp = *(const float4*)(gpart + (size_t)ks*16*2048 + (size_t)b*2048 + j*4);
        gi += gp.x; gf += gp.y; gg += gp.z; go += gp.w;
    }
    float cn = sigmf(gf)*c[b*512+j] + sigmf(gi)*tanhf(gg);
    float hn = sigmf(go)*tanhf(cn);
    c[b*512+j] = cn; h[b*512+j] = hn; hsh[j] = hn;
    __syncthreads();
    int o = j >> 2, sub = j & 3;
    float p = 0.f;
    if (o < 99) {
        const float* hk = hsh + sub*128;
        const float* wk = dwT + (size_t)sub*128*99 + o;
        for (int k = 0; k < 128; ++k) p = fmaf(hk[k], wk[(size_t)k*99], p);
    }
    p += __shfl_xor(p, 1, 4); p += __shfl_xor(p, 2, 4);
    if (o < 99 && sub == 0) out[b*99 + o] = p + dnb[o];
}

// ---------------- launch ----------------
extern "C" void kernel_launch(void* const* d_in, const int* in_sizes, int n_in,
                              void* d_out, int out_size, void* d_ws, size_t ws_size,
                              hipStream_t stream)
{
    (void)in_sizes; (void)n_in; (void)out_size; (void)ws_size;
    const float* x = (const float*)d_in[0];
    const float* convw[7]; const float* convb[7];
    for (int i = 0; i < 7; ++i) { convw[i] = (const float*)d_in[1+2*i]; convb[i] = (const float*)d_in[2+2*i]; }
    const float* lw   = (const float*)d_in[15];
    const float* lr   = (const float*)d_in[16];
    const float* lbi  = (const float*)d_in[17];
    const float* lbh  = (const float*)d_in[18];
    const float* encW = (const float*)d_in[19];
    const float* encB = (const float*)d_in[20];
    const float* dpw  = (const float*)d_in[21];
    const float* dpb  = (const float*)d_in[22];
    const float* vw   = (const float*)d_in[23];
    const float* dwih = (const float*)d_in[24];
    const float* dwhh = (const float*)d_in[25];
    const float* dbih = (const float*)d_in[26];
    const float* dbhh = (const float*)d_in[27];
    const float* dnw  = (const float*)d_in[28];
    const float* dnb  = (const float*)d_in[29];
    float* outp = (float*)d_out;

    float* ws    = (float*)d_ws;
    float* bufA  = ws;                       // 8,388,608
    float* bufB  = ws + 8388608;             // 8,388,608
    float* wscr  = ws + 16777216;            // 2,359,296 (conv weight split scratch)
    float* S0    = ws + 19136512;            // 499,712 (seq ping)
    float* SY    = ws + 19636224;            // 499,712 (seq pong)
    float* xg_f  = ws + 20135936;            // 999,424
    float* xg_b  = ws + 21135360;            // 999,424
    float* whhBf = ws + 22134784;            // 1,048,576 floats (bf16 whh, 2M shorts)
    float* encb  = ws + 24231936;            // 249,856
    float* dpwT  = ws + 24481792;            // 131,072
    float* dwT   = ws + 24612864;            // 50,688
    float* hbuf  = ws + 24663552;            // 8,192
    float* cbuf  = ws + 24671744;            // 8,192
    float* ctxb  = ws + 24679936;            // 8,192
    float* gpart = ws + 24688128;            // 131,072 -> end 24,819,200
    float* wihT4 = bufA;                     // decoder wih [0 .. 1,048,576) of bufA
    float* whh2T4= bufB;                     // decoder whh [0 .. 1,048,576) of bufB
    short* wgB   = (short*)(bufA + 1048576); // lstm gate frag split: 8.4M shorts (4.2M floats)
    short* whhB  = (short*)whhBf;

    short* whi = (short*)wscr;

    // ---- convs (L0 fused into L1) ----
    {
        int Wel = 9*(128/16)*(64/32)*512;    // 73,728
        wsplit<<<(Wel/8+255)/256, 256, 0, stream>>>(convw[1], whi, whi+Wel, 128, 64, 3, Wel/8);
        conv_mfma<3,2,2,2,1,true><<<dim3(4,32,16), 256, 0, stream>>>(
            x, whi, convb[1], bufA, 64,64,256,128, 32,128, Wel, convw[0], convb[0]);
    }
    {
        int Wel = 9*(256/16)*(128/32)*512;   // 294,912
        wsplit<<<(Wel/8+255)/256, 256, 0, stream>>>(convw[2], whi, whi+Wel, 256, 128, 3, Wel/8);
        conv_mfma<3,2,2,1,1,false><<<dim3(3,16,32), 256, 0, stream>>>(
            bufA, whi, convb[2], bufB, 128,32,128,256, 16,127, Wel, nullptr, nullptr);
    }
    {
        int Wel = 9*(512/16)*(256/32)*512;   // 1,179,648
        wsplit<<<(Wel/8+255)/256, 256, 0, stream>>>(convw[3], whi, whi+Wel, 512, 256, 3, Wel/8);
        conv_mfma<3,2,2,1,1,false><<<dim3(2,8,64), 256, 0, stream>>>(
            bufB, whi, convb[3], bufA, 256,16,127,512, 8,126, Wel, nullptr, nullptr);
    }
    {
        int Wel = 9*(512/16)*(512/32)*512;   // 2,359,296
        wsplit<<<(Wel/8+255)/256, 256, 0, stream>>>(convw[4], whi, whi+Wel, 512, 512, 3, Wel/8);
        conv_mfma<3,2,2,2,1,false><<<dim3(2,4,64), 256, 0, stream>>>(
            bufA, whi, convb[4], bufB, 512,8,126,512, 4,63, Wel, nullptr, nullptr);
    }
    {
        int Wel = 9*(512/16)*(512/32)*512;
        wsplit<<<(Wel/8+255)/256, 256, 0, stream>>>(convw[5], whi, whi+Wel, 512, 512, 3, Wel/8);
        conv_mfma<3,2,2,1,1,false><<<dim3(1,2,64), 256, 0, stream>>>(
            bufB, whi, convb[5], bufA, 512,4,63,512, 2,62, Wel, nullptr, nullptr);
    }
    {
        int Wel = 4*(512/16)*(512/32)*512;   // 1,048,576
        wsplit<<<(Wel/8+255)/256, 256, 0, stream>>>(convw[6], whi, whi+Wel, 512, 512, 2, Wel/8);
        conv_mfma<2,1,1,1,0,false><<<dim3(1,1,64), 256, 0, stream>>>(
            bufA, whi, convb[6], S0, 512,2,62,512, 1,61, Wel, nullptr, nullptr);
    }

    // ---- weight relayouts (bufA/bufB conv use done) ----
    wsplit_g<<<dim3(256, 8), 256, 0, stream>>>(lw, wgB);
    pack_whh_bf16<<<(8*1024*256 + 255)/256, 256, 0, stream>>>(lr, whhB);
    transpose2d<<<(256*512 + 255)/256, 256, 0, stream>>>(dpw, dpwT, 256, 512);
    transpose_w4<<<(2048*512 + 255)/256, 256, 0, stream>>>(dwih, wihT4);
    transpose_w4<<<(2048*512 + 255)/256, 256, 0, stream>>>(dwhh, whh2T4);
    transpose2d<<<(99*512 + 255)/256, 256, 0, stream>>>(dnw, dwT, 99, 512);

    // ---- 4 BiLSTM layers ----
    const int T = 61, M = 16*T;
    float* cur = S0; float* nxt = SY;
    for (int L = 0; L < 4; ++L) {
        int s0 = 2*L;
        gemm_mfma<<<dim3(16, 8, 2), 256, 0, stream>>>(cur, wgB, lbi, lbh, xg_f, xg_b, M, s0);
        lstm_scan3<<<dim3(16,2), 1024, 0, stream>>>(xg_f, xg_b,
            whhB + (size_t)s0*262144, whhB + (size_t)(s0+1)*262144, nxt, T);
        float* tmp = cur; cur = nxt; nxt = tmp;
    }
    // cur = S0 = final seq [16][61][512]

    // ---- enc projection ----
    gemm_nt<<<dim3(4, (M+63)/64), 256, 0, stream>>>(cur, encW, encB, nullptr, encb, M, 256, 512);

    // ---- decoder: 25 batched steps ----
    zero_hc<<<32, 256, 0, stream>>>(hbuf, cbuf);
    for (int step = 0; step < 25; ++step) {
        dec_att<<<16, 256, 0, stream>>>(hbuf, cur, encb, dpwT, dpb, vw, ctxb, T);
        gates_part<<<dim3(4,4), 256, 0, stream>>>(ctxb, hbuf, wihT4, whh2T4, gpart);
        cell_dense<<<16, 512, 0, stream>>>(hbuf, cbuf, gpart, dbih, dbhh, dwT, dnb,
                                           outp + (size_t)step*16*99);
    }
}

// Round 6
// 4707.682 us; speedup vs baseline: 6.0300x; 1.0793x over previous
//
#include <hip/hip_runtime.h>
#include <math.h>

typedef short bf16x8 __attribute__((ext_vector_type(8)));
typedef float f32x4  __attribute__((ext_vector_type(4)));

__device__ __forceinline__ float sigmf(float x){ return 1.f/(1.f+expf(-x)); }
__device__ __forceinline__ short f2bf(float f){
    unsigned u = __float_as_uint(f);
    u = (u + 0x7FFFu + ((u>>16)&1u)) >> 16;
    return (short)u;
}
__device__ __forceinline__ float bf2f(short s){
    return __uint_as_float(((unsigned)(unsigned short)s) << 16);
}

// ---------------- conv weight split into MFMA A-fragment order ----------------
__global__ void wsplit(const float* __restrict__ w, short* __restrict__ whi, short* __restrict__ wlo,
                       int Cout, int Cin, int KW, int total)
{
    int idx = blockIdx.x*256 + threadIdx.x;
    if (idx >= total) return;
    int l = idx & 63; int t = idx >> 6;
    int KST = Cin >> 5;
    int ks = t % KST; t /= KST;
    int nCoQ = Cout >> 4;
    int coQ = t % nCoQ; int kk = t / nCoQ;
    int ky = kk / KW, kx = kk % KW;
    int co = coQ*16 + (l & 15);
    int ci = ks*32 + (l >> 4)*8;
    bf16x8 h, lo;
#pragma unroll
    for (int e = 0; e < 8; ++e) {
        float wv = w[(((size_t)co*Cin + ci + e)*KW + ky)*KW + kx];
        short hb = f2bf(wv);
        h[e] = hb;
        lo[e] = f2bf(wv - bf2f(hb));
    }
    ((bf16x8*)whi)[idx] = h;
    ((bf16x8*)wlo)[idx] = lo;
}

// ---------------- lstm gate-weight split into fragment order ----------------
__global__ void wsplit_g(const float* __restrict__ w, short* __restrict__ out)
{
    int slot = blockIdx.y;
    int i = blockIdx.x*256 + threadIdx.x;
    int l = i & 63, t = i >> 6;
    int kc = t & 15, nQ = t >> 4;
    int n = nQ*16 + (l & 15);
    int k = kc*32 + (l >> 4)*8;
    const float* src = w + ((size_t)slot*1024 + n)*512 + k;
    bf16x8 h, lo;
#pragma unroll
    for (int e = 0; e < 8; ++e) {
        float wv = src[e];
        short hb = f2bf(wv);
        h[e] = hb;
        lo[e] = f2bf(wv - bf2f(hb));
    }
    short* o = out + (size_t)slot*1048576;
    ((bf16x8*)o)[i] = h;
    ((bf16x8*)(o + 524288))[i] = lo;
}

// ---------------- MFMA conv + bias + relu + maxpool ----------------
template<int KW, int PKH, int PKW, int PSW, int PAD, bool FUSE0>
__launch_bounds__(256)
__global__ void conv_mfma(const float* __restrict__ in, const short* __restrict__ wm,
                          const float* __restrict__ bias, float* __restrict__ out,
                          int Cin, int H, int W, int Cout, int Hp, int Wp, int Wel,
                          const float* __restrict__ w0, const float* __restrict__ b0)
{
    constexpr int TAPS = KW*KW;
    constexpr int SR   = PKH + KW - 1;
    constexpr int XT   = 64;
    constexpr int XTH  = 67;
    constexpr int POB  = (XT - PKW)/PSW + 1;
    __shared__ union {
        short s[2][16][XTH][8];
        float y[64][132];
    } u;
    __shared__ float w0s[640];

    const int tid  = threadIdx.x;
    const int lane = tid & 63;
    const int wid  = tid >> 6;
    const int l15  = lane & 15, l4 = lane >> 4;
    const int nCoT = Cout >> 7;
    const int b    = blockIdx.z / nCoT;
    const int ct   = blockIdx.z % nCoT;
    const int co_blk = ct << 7;
    const int hp   = blockIdx.y;
    const int px0  = blockIdx.x * POB;
    const int x0   = px0 * PSW;
    const int y0   = hp * PKH;
    const int cow  = wid >> 1;
    const int xw   = (wid & 1) * 32;
    const int KST  = Cin >> 5;
    const int nCoQ = Cout >> 4;

    if constexpr (FUSE0) {
        for (int i = tid; i < 640; i += 256) w0s[i] = (i < 576) ? w0[i] : b0[i-576];
    }

    f32x4 acc[4][2][PKH];
#pragma unroll
    for (int c = 0; c < 4; ++c)
#pragma unroll
        for (int xf = 0; xf < 2; ++xf)
#pragma unroll
            for (int r = 0; r < PKH; ++r) acc[c][xf][r] = (f32x4){0.f,0.f,0.f,0.f};

    const float* inb = FUSE0 ? (in + (size_t)b*128*512) : (in + (size_t)b*H*W*Cin);

    for (int ci0 = 0; ci0 < Cin; ci0 += 32) {
        __syncthreads();
        constexpr int ITEMS = SR*XTH*4;
        for (int it = tid; it < ITEMS; it += 256) {
            int kslot = it & 3;
            int x  = (it >> 2) % XTH;
            int r  = (it >> 2) / XTH;
            int y  = y0 - PAD + r;
            int xg = x0 - PAD + x;
            float v[8];
            if constexpr (FUSE0) {
                if (y >= 0 && y < H && xg >= 0 && xg < W) {
                    float xin[4][4];
                    int iy0 = 2*y - 1, ix0 = 2*xg - 1;
#pragma unroll
                    for (int dy = 0; dy < 4; ++dy) {
                        int iy = iy0 + dy;
                        bool oky = (iy >= 0) && (iy < 128);
#pragma unroll
                        for (int dx = 0; dx < 4; ++dx) {
                            int ix = ix0 + dx;
                            xin[dy][dx] = (oky && ix >= 0 && ix < 512) ? inb[(size_t)iy*512 + ix] : 0.f;
                        }
                    }
#pragma unroll
                    for (int c = 0; c < 8; ++c) {
                        int co = ci0 + kslot*8 + c;
                        const float* w9 = &w0s[co*9];
                        float p00=0.f,p01=0.f,p10=0.f,p11=0.f;
#pragma unroll
                        for (int ky = 0; ky < 3; ++ky)
#pragma unroll
                            for (int kx = 0; kx < 3; ++kx) {
                                float wv = w9[ky*3+kx];
                                p00 = fmaf(xin[ky  ][kx  ], wv, p00);
                                p01 = fmaf(xin[ky  ][kx+1], wv, p01);
                                p10 = fmaf(xin[ky+1][kx  ], wv, p10);
                                p11 = fmaf(xin[ky+1][kx+1], wv, p11);
                            }
                        float m = fmaxf(fmaxf(p00,p01), fmaxf(p10,p11)) + w0s[576+co];
                        v[c] = fmaxf(m, 0.f);
                    }
                } else {
#pragma unroll
                    for (int c = 0; c < 8; ++c) v[c] = 0.f;
                }
            } else {
                if (y >= 0 && y < H && xg >= 0 && xg < W) {
                    const float* p = inb + ((size_t)y*W + xg)*Cin + ci0 + kslot*8;
                    float4 a = *(const float4*)p;
                    float4 bq = *(const float4*)(p+4);
                    v[0]=a.x; v[1]=a.y; v[2]=a.z; v[3]=a.w;
                    v[4]=bq.x; v[5]=bq.y; v[6]=bq.z; v[7]=bq.w;
                } else {
#pragma unroll
                    for (int c = 0; c < 8; ++c) v[c] = 0.f;
                }
            }
            bf16x8 h8, l8;
#pragma unroll
            for (int c = 0; c < 8; ++c) {
                short hb = f2bf(v[c]);
                h8[c] = hb;
                l8[c] = f2bf(v[c] - bf2f(hb));
            }
            *(bf16x8*)&u.s[0][r*4+kslot][x][0] = h8;
            *(bf16x8*)&u.s[1][r*4+kslot][x][0] = l8;
        }
        __syncthreads();

        const int ks = ci0 >> 5;
        for (int kk = 0; kk < TAPS; ++kk) {
            const int ky = kk / KW, kx = kk % KW;
            bf16x8 ah[4], al[4];
            const size_t abase = (((size_t)kk*nCoQ + (co_blk>>4) + cow*4)*KST + ks)*512 + lane*8;
            const size_t cstr  = (size_t)KST*512;
#pragma unroll
            for (int c = 0; c < 4; ++c) {
                ah[c] = *(const bf16x8*)(wm + abase + c*cstr);
                al[c] = *(const bf16x8*)(wm + Wel + abase + c*cstr);
            }
#pragma unroll
            for (int r = 0; r < PKH; ++r) {
                const int sr = r + ky;
                bf16x8 bh[2], bl[2];
#pragma unroll
                for (int xf = 0; xf < 2; ++xf) {
                    int xcol = xw + xf*16 + l15 + kx;
                    bh[xf] = *(const bf16x8*)&u.s[0][sr*4 + l4][xcol][0];
                    bl[xf] = *(const bf16x8*)&u.s[1][sr*4 + l4][xcol][0];
                }
#pragma unroll
                for (int c = 0; c < 4; ++c)
#pragma unroll
                    for (int xf = 0; xf < 2; ++xf) {
                        acc[c][xf][r] = __builtin_amdgcn_mfma_f32_16x16x32_bf16(ah[c], bh[xf], acc[c][xf][r], 0,0,0);
                        acc[c][xf][r] = __builtin_amdgcn_mfma_f32_16x16x32_bf16(ah[c], bl[xf], acc[c][xf][r], 0,0,0);
                        acc[c][xf][r] = __builtin_amdgcn_mfma_f32_16x16x32_bf16(al[c], bh[xf], acc[c][xf][r], 0,0,0);
                    }
            }
        }
    }

    __syncthreads();
#pragma unroll
    for (int c = 0; c < 4; ++c) {
        int co_l = cow*64 + c*16 + l4*4;
        float4 b4 = *(const float4*)&bias[co_blk + co_l];
#pragma unroll
        for (int xf = 0; xf < 2; ++xf) {
            f32x4 v = acc[c][xf][0];
            if (PKH == 2) {
                f32x4 v1 = acc[c][xf][1];
                v[0]=fmaxf(v[0],v1[0]); v[1]=fmaxf(v[1],v1[1]);
                v[2]=fmaxf(v[2],v1[2]); v[3]=fmaxf(v[3],v1[3]);
            }
            v[0]+=b4.x; v[1]+=b4.y; v[2]+=b4.z; v[3]+=b4.w;
            int x = xw + xf*16 + l15;
            *(f32x4*)&u.y[x][co_l] = v;
        }
    }
    __syncthreads();
    for (int i = tid; i < POB*128; i += 256) {
        int co = i & 127, p = i >> 7;
        int x = p * PSW;
        float v = u.y[x][co];
        if (PKW == 2) v = fmaxf(v, u.y[x+1][co]);
        v = fmaxf(v, 0.f);
        int px = px0 + p;
        if (px < Wp)
            out[(((size_t)b*Hp + hp)*Wp + px)*Cout + co_blk + co] = v;
    }
}

// ---------------- MFMA split-bf16 gate GEMM ----------------
__launch_bounds__(256)
__global__ void gemm_mfma(const float* __restrict__ A, const short* __restrict__ wg,
                          const float* __restrict__ bi, const float* __restrict__ bh,
                          float* __restrict__ Cf, float* __restrict__ Cb,
                          int M, int s0)
{
    __shared__ short sa[2][4][64][8];
    const int tid = threadIdx.x;
    const int lane = tid & 63;
    const int wid = tid >> 6;
    const int l15 = lane & 15, l4 = lane >> 4;
    const int cow = wid >> 1;
    const int xw  = wid & 1;
    const int m0 = blockIdx.x * 64;
    const int n0 = blockIdx.y * 128;
    const int slot = s0 + blockIdx.z;
    const short* whi = wg + (size_t)slot * 1048576;
    const short* wlo = whi + 524288;
    float* C = blockIdx.z ? Cb : Cf;
    const float* b1 = bi + slot*1024;
    const float* b2 = bh + slot*1024;

    const int mg  = wid;
    const int pos = tid & 63;
    const int sm  = mg*16 + (pos & 15);
    const int skl = pos >> 4;
    const int gm  = m0 + sm;
    const int nQb = blockIdx.y*8 + cow*4;

    f32x4 acc[4][2];
#pragma unroll
    for (int c = 0; c < 4; ++c)
#pragma unroll
        for (int xf = 0; xf < 2; ++xf) acc[c][xf] = (f32x4){0.f,0.f,0.f,0.f};

    for (int kc = 0; kc < 16; ++kc) {
        __syncthreads();
        {
            float v[8];
            if (gm < M) {
                const float* ap = A + (size_t)gm*512 + kc*32 + skl*8;
                float4 q0 = *(const float4*)ap;
                float4 q1 = *(const float4*)(ap+4);
                v[0]=q0.x; v[1]=q0.y; v[2]=q0.z; v[3]=q0.w;
                v[4]=q1.x; v[5]=q1.y; v[6]=q1.z; v[7]=q1.w;
            } else {
#pragma unroll
                for (int e = 0; e < 8; ++e) v[e] = 0.f;
            }
            bf16x8 h8, l8;
#pragma unroll
            for (int e = 0; e < 8; ++e) {
                short hb = f2bf(v[e]);
                h8[e] = hb;
                l8[e] = f2bf(v[e] - bf2f(hb));
            }
            *(bf16x8*)&sa[0][mg][pos][0] = h8;
            *(bf16x8*)&sa[1][mg][pos][0] = l8;
        }
        __syncthreads();

        bf16x8 ah[4], al[4];
#pragma unroll
        for (int c = 0; c < 4; ++c) {
            size_t off = (((size_t)(nQb + c)*16 + kc)*64 + lane)*8;
            ah[c] = *(const bf16x8*)(whi + off);
            al[c] = *(const bf16x8*)(wlo + off);
        }
        bf16x8 bhv[2], blv[2];
#pragma unroll
        for (int xf = 0; xf < 2; ++xf) {
            bhv[xf] = *(const bf16x8*)&sa[0][xw*2+xf][lane][0];
            blv[xf] = *(const bf16x8*)&sa[1][xw*2+xf][lane][0];
        }
#pragma unroll
        for (int c = 0; c < 4; ++c)
#pragma unroll
            for (int xf = 0; xf < 2; ++xf) {
                acc[c][xf] = __builtin_amdgcn_mfma_f32_16x16x32_bf16(ah[c], bhv[xf], acc[c][xf], 0,0,0);
                acc[c][xf] = __builtin_amdgcn_mfma_f32_16x16x32_bf16(ah[c], blv[xf], acc[c][xf], 0,0,0);
                acc[c][xf] = __builtin_amdgcn_mfma_f32_16x16x32_bf16(al[c], bhv[xf], acc[c][xf], 0,0,0);
            }
    }

#pragma unroll
    for (int c = 0; c < 4; ++c) {
        int n = n0 + cow*64 + c*16 + l4*4;
        float4 bb1 = *(const float4*)&b1[n];
        float4 bb2 = *(const float4*)&b2[n];
#pragma unroll
        for (int xf = 0; xf < 2; ++xf) {
            int m = m0 + xw*32 + xf*16 + l15;
            if (m < M) {
                f32x4 a = acc[c][xf];
                float4 o;
                o.x = a[0] + bb1.x + bb2.x;
                o.y = a[1] + bb1.y + bb2.y;
                o.z = a[2] + bb1.z + bb2.z;
                o.w = a[3] + bb1.w + bb2.w;
                *(float4*)&C[(size_t)m*1024 + n] = o;
            }
        }
    }
}

// ---------------- fp32 GEMM (enc projection) ----------------
__launch_bounds__(256)
__global__ void gemm_nt(const float* __restrict__ A, const float* __restrict__ Bm,
                        const float* __restrict__ bias1, const float* __restrict__ bias2,
                        float* __restrict__ C, int M, int N, int K)
{
    __shared__ float As[16][68];
    __shared__ float Bs[16][68];
    const int tid = threadIdx.x;
    const int tx = tid & 15, ty = tid >> 4;
    const int row0 = blockIdx.y*64, col0 = blockIdx.x*64;
    float acc[4][4] = {};
    for (int k0 = 0; k0 < K; k0 += 16) {
#pragma unroll
        for (int i = 0; i < 4; ++i) {
            int e  = tid + i*256;
            int r  = e >> 4, kk = e & 15;
            int gr = row0 + r, gk = k0 + kk;
            As[kk][r] = (gr < M) ? A[(size_t)gr*K + gk] : 0.f;
            int gc = col0 + r;
            Bs[kk][r] = (gc < N) ? Bm[(size_t)gc*K + gk] : 0.f;
        }
        __syncthreads();
#pragma unroll
        for (int kk = 0; kk < 16; ++kk) {
            float av[4], bv[4];
#pragma unroll
            for (int i=0;i<4;++i) av[i] = As[kk][ty*4+i];
#pragma unroll
            for (int j=0;j<4;++j) bv[j] = Bs[kk][tx*4+j];
#pragma unroll
            for (int i=0;i<4;++i)
#pragma unroll
                for (int j=0;j<4;++j) acc[i][j] = fmaf(av[i], bv[j], acc[i][j]);
        }
        __syncthreads();
    }
#pragma unroll
    for (int i=0;i<4;++i)
#pragma unroll
        for (int j=0;j<4;++j) {
            int r = row0 + ty*4 + i, cc = col0 + tx*4 + j;
            if (r < M && cc < N) {
                float v = acc[i][j];
                if (bias1) v += bias1[cc];
                if (bias2) v += bias2[cc];
                C[(size_t)r*N + cc] = v;
            }
        }
}

// ---------------- transposes / relayouts ----------------
__global__ void transpose2d(const float* __restrict__ in, float* __restrict__ out, int R, int C)
{
    int idx = blockIdx.x*256 + threadIdx.x;
    if (idx >= R*C) return;
    int r = idx / C, c = idx % C;
    out[(size_t)c*R + r] = in[idx];
}

__global__ void transpose_w4(const float* __restrict__ in, float* __restrict__ out)
{
    int idx = blockIdx.x*256 + threadIdx.x;
    if (idx >= 2048*512) return;
    int row = idx >> 9, k = idx & 511;
    int gate = row >> 9, j = row & 511;
    out[((size_t)k*512 + j)*4 + gate] = in[idx];
}

// ---------------- flags zero ----------------
__global__ void zero_flags(int* __restrict__ flags, int n)
{
    int i = blockIdx.x*256 + threadIdx.x;
    if (i < n) flags[i] = 0;
}

// ---------------- LSTM spin scan: LDS-resident weights, cross-block h exchange ----------------
// grid (8 jsplit, 4 bgroup, 2 dir), 256 threads.
// LDS: w fp32 [256k][32j][4g] 128KB + hcur[256][4] 4KB + parts[4g][4b][8ks][32j] 16KB
__launch_bounds__(256)
__global__ void lstm_spin(const float* __restrict__ xgf, const float* __restrict__ xgb,
                          const float* __restrict__ whh, float* __restrict__ hout,
                          float* __restrict__ hx, int* __restrict__ flags,
                          int T, int s0)
{
    __shared__ float wlds[32768];    // [k][jl][g]
    __shared__ float hcur[1024];     // [k][b]
    __shared__ float parts[4096];    // [g][b][ks][jl]
    const int tid = threadIdx.x;
    const int jq = blockIdx.x, bg = blockIdx.y, dir = blockIdx.z;
    const int j0 = jq*32, b0 = bg*4;
    const float* W = whh + (size_t)(s0 + dir)*262144;   // [1024 g][256 k]

    // stage weight slice: wlds[(k*32+jl)*4+g] = W[(g*256 + j0+jl)*256 + k]
    for (int idx = tid; idx < 32768; idx += 256) {
        int k = idx & 255, r = idx >> 8;
        int jl = r & 31, g = r >> 5;
        wlds[(k*32 + jl)*4 + g] = W[((size_t)g*256 + j0 + jl)*256 + k];
    }
    const float* xg = dir ? xgb : xgf;
    float* hxg = hx + (size_t)(dir*4 + bg)*2048;   // 2 parity slots x 1024
    int* flg = flags + (dir*4 + bg)*61;
    const int jl_c = tid & 31, b_c = tid >> 5;     // cell mapping (tid<128)
    const int ks = tid >> 5, jl = tid & 31;        // matvec mapping
    float cc = 0.f;
    __syncthreads();

    for (int s = 0; s < T; ++s) {
        const int t = dir ? (T-1-s) : s;
        float xgv0=0.f, xgv1=0.f, xgv2=0.f, xgv3=0.f;
        if (tid < 128) {
            const float* xr = xg + ((size_t)(b0 + b_c)*T + t)*1024 + (j0 + jl_c);
            xgv0 = xr[0]; xgv1 = xr[256]; xgv2 = xr[512]; xgv3 = xr[768];
        }
        if (s == 0) {
            for (int i = tid; i < 1024; i += 256) hcur[i] = 0.f;
        } else {
            int* fp = flg + (s-1);
            while (__hip_atomic_load(fp, __ATOMIC_ACQUIRE, __HIP_MEMORY_SCOPE_AGENT) < 8)
                __builtin_amdgcn_s_sleep(1);
            const float* hsrc = hxg + ((s-1)&1)*1024 + tid*4;
            float v0 = __hip_atomic_load(hsrc+0, __ATOMIC_RELAXED, __HIP_MEMORY_SCOPE_AGENT);
            float v1 = __hip_atomic_load(hsrc+1, __ATOMIC_RELAXED, __HIP_MEMORY_SCOPE_AGENT);
            float v2 = __hip_atomic_load(hsrc+2, __ATOMIC_RELAXED, __HIP_MEMORY_SCOPE_AGENT);
            float v3 = __hip_atomic_load(hsrc+3, __ATOMIC_RELAXED, __HIP_MEMORY_SCOPE_AGENT);
            hcur[tid*4+0]=v0; hcur[tid*4+1]=v1; hcur[tid*4+2]=v2; hcur[tid*4+3]=v3;
        }
        __syncthreads();

        // matvec: thread (ks,jl): 32 k x 4 gates x 4 batches
        float a[4][4];
#pragma unroll
        for (int g = 0; g < 4; ++g)
#pragma unroll
            for (int b = 0; b < 4; ++b) a[g][b] = 0.f;
        for (int kk = 0; kk < 32; ++kk) {
            int k = ks*32 + kk;
            float4 wv = *(const float4*)&wlds[(k*32 + jl)*4];
            float4 hv = *(const float4*)&hcur[k*4];
            a[0][0] = fmaf(wv.x, hv.x, a[0][0]); a[0][1] = fmaf(wv.x, hv.y, a[0][1]);
            a[0][2] = fmaf(wv.x, hv.z, a[0][2]); a[0][3] = fmaf(wv.x, hv.w, a[0][3]);
            a[1][0] = fmaf(wv.y, hv.x, a[1][0]); a[1][1] = fmaf(wv.y, hv.y, a[1][1]);
            a[1][2] = fmaf(wv.y, hv.z, a[1][2]); a[1][3] = fmaf(wv.y, hv.w, a[1][3]);
            a[2][0] = fmaf(wv.z, hv.x, a[2][0]); a[2][1] = fmaf(wv.z, hv.y, a[2][1]);
            a[2][2] = fmaf(wv.z, hv.z, a[2][2]); a[2][3] = fmaf(wv.z, hv.w, a[2][3]);
            a[3][0] = fmaf(wv.w, hv.x, a[3][0]); a[3][1] = fmaf(wv.w, hv.y, a[3][1]);
            a[3][2] = fmaf(wv.w, hv.z, a[3][2]); a[3][3] = fmaf(wv.w, hv.w, a[3][3]);
        }
#pragma unroll
        for (int g = 0; g < 4; ++g)
#pragma unroll
            for (int b = 0; b < 4; ++b)
                parts[((g*4 + b)*8 + ks)*32 + jl] = a[g][b];
        __syncthreads();

        if (tid < 128) {
            float gi = xgv0, gf = xgv1, gg = xgv2, go = xgv3;
#pragma unroll
            for (int k2 = 0; k2 < 8; ++k2) {
                gi += parts[((0*4 + b_c)*8 + k2)*32 + jl_c];
                gf += parts[((1*4 + b_c)*8 + k2)*32 + jl_c];
                gg += parts[((2*4 + b_c)*8 + k2)*32 + jl_c];
                go += parts[((3*4 + b_c)*8 + k2)*32 + jl_c];
            }
            cc = sigmf(gf)*cc + sigmf(gi)*tanhf(gg);
            float h = sigmf(go)*tanhf(cc);
            hout[((size_t)(b0 + b_c)*T + t)*512 + dir*256 + j0 + jl_c] = h;
            __hip_atomic_store(hxg + (s&1)*1024 + (j0 + jl_c)*4 + b_c, h,
                               __ATOMIC_RELAXED, __HIP_MEMORY_SCOPE_AGENT);
        }
        __syncthreads();   // drains the agent stores (vmcnt) before release
        if (tid == 0)
            __hip_atomic_fetch_add(flg + s, 1, __ATOMIC_RELEASE, __HIP_MEMORY_SCOPE_AGENT);
    }
}

// ---------------- decoder: batched per-step kernels ----------------
__global__ void zero_hc(float* __restrict__ h, float* __restrict__ c)
{
    int i = blockIdx.x*256 + threadIdx.x;
    if (i < 16*512) { h[i] = 0.f; c[i] = 0.f; }
}

__launch_bounds__(256)
__global__ void dec_att(const float* __restrict__ h, const float* __restrict__ seq,
                        const float* __restrict__ enc, const float* __restrict__ dpwT,
                        const float* __restrict__ dpb, const float* __restrict__ vw,
                        float* __restrict__ ctx, int T)
{
    __shared__ float hsm[512], dec[256], sc[64];
    const int b = blockIdx.x, tid = threadIdx.x;
    hsm[tid]     = h[b*512 + tid];
    hsm[256+tid] = h[b*512 + 256 + tid];
    __syncthreads();
    float s = dpb[tid];
    for (int k = 0; k < 512; ++k) s = fmaf(hsm[k], dpwT[(size_t)k*256 + tid], s);
    dec[tid] = s;
    __syncthreads();
    {
        int t = tid >> 2, sub = tid & 3;
        float p = 0.f;
        if (t < T) {
            const float* er = enc + ((size_t)b*T + t)*256 + sub*64;
            const float* dc = dec + sub*64;
            const float* vv = vw + sub*64;
            for (int a = 0; a < 64; ++a) p = fmaf(tanhf(er[a] + dc[a]), vv[a], p);
        }
        p += __shfl_xor(p, 1, 4); p += __shfl_xor(p, 2, 4);
        if (t < T && sub == 0) sc[t] = p;
    }
    __syncthreads();
    if (tid < 64) {
        float v = (tid < T) ? sc[tid] : -1e30f;
        float m = v;
        for (int o = 1; o < 64; o <<= 1) m = fmaxf(m, __shfl_xor(m, o, 64));
        float e = (tid < T) ? expf(v - m) : 0.f;
        float ssum = e;
        for (int o = 1; o < 64; o <<= 1) ssum += __shfl_xor(ssum, o, 64);
        if (tid < T) sc[tid] = e / ssum;
    }
    __syncthreads();
#pragma unroll
    for (int half = 0; half < 2; ++half) {
        int col = tid + half*256;
        float acc = 0.f;
        const float* sr = seq + (size_t)b*T*512 + col;
        for (int t = 0; t < T; ++t) acc = fmaf(sc[t], sr[(size_t)t*512], acc);
        ctx[b*512 + col] = acc;
    }
}

__launch_bounds__(256)
__global__ void gates_part(const float* __restrict__ ctx, const float* __restrict__ h,
                           const float* __restrict__ wi4, const float* __restrict__ wh4,
                           float* __restrict__ gpart)
{
    __shared__ float xs[16][128], hsh[16][128];
    const int jt = blockIdx.x, ks = blockIdx.y;
    const int tid = threadIdx.x;
    const int jl = tid & 127, bh = tid >> 7;
    const int j = jt*128 + jl;
    const int k0 = ks*128;
    for (int idx = tid; idx < 2048; idx += 256) {
        int bb = idx >> 7, kk = idx & 127;
        xs[bb][kk]  = ctx[bb*512 + k0 + kk];
        hsh[bb][kk] = h[bb*512 + k0 + kk];
    }
    __syncthreads();
    float acc[8][4];
#pragma unroll
    for (int bi=0;bi<8;++bi)
#pragma unroll
        for (int g=0;g<4;++g) acc[bi][g]=0.f;
    const float4* wip = (const float4*)wi4 + (size_t)k0*512 + j;
    const float4* whp = (const float4*)wh4 + (size_t)k0*512 + j;
#pragma unroll 2
    for (int kk = 0; kk < 128; ++kk) {
        float4 wa = wip[(size_t)kk*512];
        float4 wb = whp[(size_t)kk*512];
#pragma unroll
        for (int bi = 0; bi < 8; ++bi) {
            int bb = bh*8 + bi;
            float xv = xs[bb][kk], hv = hsh[bb][kk];
            acc[bi][0] = fmaf(xv, wa.x, fmaf(hv, wb.x, acc[bi][0]));
            acc[bi][1] = fmaf(xv, wa.y, fmaf(hv, wb.y, acc[bi][1]));
            acc[bi][2] = fmaf(xv, wa.z, fmaf(hv, wb.z, acc[bi][2]));
            acc[bi][3] = fmaf(xv, wa.w, fmaf(hv, wb.w, acc[bi][3]));
        }
    }
    float* gp = gpart + (size_t)ks*16*2048;
#pragma unroll
    for (int bi = 0; bi < 8; ++bi)
#pragma unroll
        for (int g = 0; g < 4; ++g)
            gp[(size_t)(bh*8+bi)*2048 + j*4 + g] = acc[bi][g];
}

__launch_bounds__(512)
__global__ void cell_dense(float* __restrict__ h, float* __restrict__ c,
                           const float* __restrict__ gpart,
                           const float* __restrict__ bih, const float* __restrict__ bhh,
                           const float* __restrict__ dwT, const float* __restrict__ dnb,
                           float* __restrict__ out)
{
    __shared__ float hsh[512];
    const int b = blockIdx.x, j = threadIdx.x;
    float gi = bih[j]        + bhh[j];
    float gf = bih[512+j]    + bhh[512+j];
    float gg = bih[1024+j]   + bhh[1024+j];
    float go = bih[1536+j]   + bhh[1536+j];
#pragma unroll
    for (int ks = 0; ks < 4; ++ks) {
        float4 gp = *(const float4*)(gpart + (size_t)ks*16*2048 + (size_t)b*2048 + j*4);
        gi += gp.x; gf += gp.y; gg += gp.z; go += gp.w;
    }
    float cn = sigmf(gf)*c[b*512+j] + sigmf(gi)*tanhf(gg);
    float hn = sigmf(go)*tanhf(cn);
    c[b*512+j] = cn; h[b*512+j] = hn; hsh[j] = hn;
    __syncthreads();
    int o = j >> 2, sub = j & 3;
    float p = 0.f;
    if (o < 99) {
        const float* hk = hsh + sub*128;
        const float* wk = dwT + (size_t)sub*128*99 + o;
        for (int k = 0; k < 128; ++k) p = fmaf(hk[k], wk[(size_t)k*99], p);
    }
    p += __shfl_xor(p, 1, 4); p += __shfl_xor(p, 2, 4);
    if (o < 99 && sub == 0) out[b*99 + o] = p + dnb[o];
}

// ---------------- launch ----------------
extern "C" void kernel_launch(void* const* d_in, const int* in_sizes, int n_in,
                              void* d_out, int out_size, void* d_ws, size_t ws_size,
                              hipStream_t stream)
{
    (void)in_sizes; (void)n_in; (void)out_size; (void)ws_size;
    const float* x = (const float*)d_in[0];
    const float* convw[7]; const float* convb[7];
    for (int i = 0; i < 7; ++i) { convw[i] = (const float*)d_in[1+2*i]; convb[i] = (const float*)d_in[2+2*i]; }
    const float* lw   = (const float*)d_in[15];
    const float* lr   = (const float*)d_in[16];
    const float* lbi  = (const float*)d_in[17];
    const float* lbh  = (const float*)d_in[18];
    const float* encW = (const float*)d_in[19];
    const float* encB = (const float*)d_in[20];
    const float* dpw  = (const float*)d_in[21];
    const float* dpb  = (const float*)d_in[22];
    const float* vw   = (const float*)d_in[23];
    const float* dwih = (const float*)d_in[24];
    const float* dwhh = (const float*)d_in[25];
    const float* dbih = (const float*)d_in[26];
    const float* dbhh = (const float*)d_in[27];
    const float* dnw  = (const float*)d_in[28];
    const float* dnb  = (const float*)d_in[29];
    float* outp = (float*)d_out;

    float* ws    = (float*)d_ws;
    float* bufA  = ws;                       // 8,388,608
    float* bufB  = ws + 8388608;             // 8,388,608
    float* wscr  = ws + 16777216;            // 2,359,296 (conv weight split scratch)
    float* S0    = ws + 19136512;            // 499,712 (seq ping)
    float* SY    = ws + 19636224;            // 499,712 (seq pong)
    float* xg_f  = ws + 20135936;            // 999,424
    float* xg_b  = ws + 21135360;            // 999,424
    float* hxfl  = ws + 22134784;            // hx 16384 floats + flags 1952 ints
    float* encb  = ws + 24231936;            // 249,856
    float* dpwT  = ws + 24481792;            // 131,072
    float* dwT   = ws + 24612864;            // 50,688
    float* hbuf  = ws + 24663552;            // 8,192
    float* cbuf  = ws + 24671744;            // 8,192
    float* ctxb  = ws + 24679936;            // 8,192
    float* gpart = ws + 24688128;            // 131,072 -> end 24,819,200
    float* wihT4 = bufA;                     // decoder wih (after convs)
    float* whh2T4= bufB;                     // decoder whh (after convs)
    short* wgB   = (short*)(bufA + 1048576); // lstm gate frag split
    float* hx    = hxfl;
    int*   flags = (int*)(hxfl + 16384);

    short* whi = (short*)wscr;

    // ---- convs (L0 fused into L1) ----
    {
        int Wel = 9*(128/16)*(64/32)*512;
        wsplit<<<(Wel/8+255)/256, 256, 0, stream>>>(convw[1], whi, whi+Wel, 128, 64, 3, Wel/8);
        conv_mfma<3,2,2,2,1,true><<<dim3(4,32,16), 256, 0, stream>>>(
            x, whi, convb[1], bufA, 64,64,256,128, 32,128, Wel, convw[0], convb[0]);
    }
    {
        int Wel = 9*(256/16)*(128/32)*512;
        wsplit<<<(Wel/8+255)/256, 256, 0, stream>>>(convw[2], whi, whi+Wel, 256, 128, 3, Wel/8);
        conv_mfma<3,2,2,1,1,false><<<dim3(3,16,32), 256, 0, stream>>>(
            bufA, whi, convb[2], bufB, 128,32,128,256, 16,127, Wel, nullptr, nullptr);
    }
    {
        int Wel = 9*(512/16)*(256/32)*512;
        wsplit<<<(Wel/8+255)/256, 256, 0, stream>>>(convw[3], whi, whi+Wel, 512, 256, 3, Wel/8);
        conv_mfma<3,2,2,1,1,false><<<dim3(2,8,64), 256, 0, stream>>>(
            bufB, whi, convb[3], bufA, 256,16,127,512, 8,126, Wel, nullptr, nullptr);
    }
    {
        int Wel = 9*(512/16)*(512/32)*512;
        wsplit<<<(Wel/8+255)/256, 256, 0, stream>>>(convw[4], whi, whi+Wel, 512, 512, 3, Wel/8);
        conv_mfma<3,2,2,2,1,false><<<dim3(2,4,64), 256, 0, stream>>>(
            bufA, whi, convb[4], bufB, 512,8,126,512, 4,63, Wel, nullptr, nullptr);
    }
    {
        int Wel = 9*(512/16)*(512/32)*512;
        wsplit<<<(Wel/8+255)/256, 256, 0, stream>>>(convw[5], whi, whi+Wel, 512, 512, 3, Wel/8);
        conv_mfma<3,2,2,1,1,false><<<dim3(1,2,64), 256, 0, stream>>>(
            bufB, whi, convb[5], bufA, 512,4,63,512, 2,62, Wel, nullptr, nullptr);
    }
    {
        int Wel = 4*(512/16)*(512/32)*512;
        wsplit<<<(Wel/8+255)/256, 256, 0, stream>>>(convw[6], whi, whi+Wel, 512, 512, 2, Wel/8);
        conv_mfma<2,1,1,1,0,false><<<dim3(1,1,64), 256, 0, stream>>>(
            bufA, whi, convb[6], S0, 512,2,62,512, 1,61, Wel, nullptr, nullptr);
    }

    // ---- weight relayouts + flags init ----
    wsplit_g<<<dim3(256, 8), 256, 0, stream>>>(lw, wgB);
    zero_flags<<<8, 256, 0, stream>>>(flags, 4*2*4*61);
    transpose2d<<<(256*512 + 255)/256, 256, 0, stream>>>(dpw, dpwT, 256, 512);
    transpose_w4<<<(2048*512 + 255)/256, 256, 0, stream>>>(dwih, wihT4);
    transpose_w4<<<(2048*512 + 255)/256, 256, 0, stream>>>(dwhh, whh2T4);
    transpose2d<<<(99*512 + 255)/256, 256, 0, stream>>>(dnw, dwT, 99, 512);

    // ---- 4 BiLSTM layers ----
    const int T = 61, M = 16*T;
    float* cur = S0; float* nxt = SY;
    for (int L = 0; L < 4; ++L) {
        int s0 = 2*L;
        gemm_mfma<<<dim3(16, 8, 2), 256, 0, stream>>>(cur, wgB, lbi, lbh, xg_f, xg_b, M, s0);
        lstm_spin<<<dim3(8, 4, 2), 256, 0, stream>>>(xg_f, xg_b, lr, nxt,
                                                     hx, flags + L*488, T, s0);
        float* tmp = cur; cur = nxt; nxt = tmp;
    }
    // cur = final seq [16][61][512]

    // ---- enc projection ----
    gemm_nt<<<dim3(4, (M+63)/64), 256, 0, stream>>>(cur, encW, encB, nullptr, encb, M, 256, 512);

    // ---- decoder: 25 batched steps ----
    zero_hc<<<32, 256, 0, stream>>>(hbuf, cbuf);
    for (int step = 0; step < 25; ++step) {
        dec_att<<<16, 256, 0, stream>>>(hbuf, cur, encb, dpwT, dpb, vw, ctxb, T);
        gates_part<<<dim3(4,4), 256, 0, stream>>>(ctxb, hbuf, wihT4, whh2T4, gpart);
        cell_dense<<<16, 512, 0, stream>>>(hbuf, cbuf, gpart, dbih, dbhh, dwT, dnb,
                                           outp + (size_t)step*16*99);
    }
}